// Round 4
// baseline (1438.983 us; speedup 1.0000x reference)
//
#include <hip/hip_runtime.h>
#include <hip/hip_bf16.h>
#include <cstdint>

typedef __hip_bfloat16 bf16;
typedef _Float16 f16;
typedef f16 f16x2 __attribute__((ext_vector_type(2)));
typedef f16 f16x8 __attribute__((ext_vector_type(8)));
typedef float f32x4 __attribute__((ext_vector_type(4)));

#define C_IN   64
#define C_HID  128
#define C_LAT  32
#define C_H    8
#define C_L    3
#define C_G    64

// Runtime input-dtype handling (harness may hand fp32 or bf16). flag==1 -> fp32.
__device__ inline float load_in(const void* p, size_t idx, int is_f32) {
    if (is_f32) return ((const float*)p)[idx];
    return __bfloat162float(((const bf16*)p)[idx]);
}

__global__ void detect_dtype(const unsigned short* __restrict__ W, int* __restrict__ flag) {
    __shared__ int cnt;
    if (threadIdx.x == 0) cnt = 0;
    __syncthreads();
    int local = 0;
    for (int i = threadIdx.x; i < 8192; i += 256) {
        int e = (W[i] >> 7) & 0xFF;
        if (e >= 135) local++;
    }
    atomicAdd(&cnt, local);
    __syncthreads();
    if (threadIdx.x == 0) *flag = (cnt > 64) ? 1 : 0;
}

__device__ inline void split16(float v, f16& hi, f16& lo) {
    hi = (f16)v;
    lo = (f16)(v - (float)hi);
}

// ---------- weight repack -> fragment-major split-f16 layout ----------
// B[((s*8 + j)*256 + t)*8 + e], j = kc*4 + hl*2 + nt
// frag(j,t): o = w*32 + nt*16 + l16;  kglob = s*64 + kc*32 + quad*8 + e
__global__ void repack_embed(const void* __restrict__ W, f16* __restrict__ B,
                             const int* __restrict__ flagp) {
    const int is_f32 = *flagp;
    int idx = blockIdx.x * blockDim.x + threadIdx.x;
    if (idx >= 16 * 8 * 256 * 8) return;          // 262144 f16
    int e = idx & 7;
    int t = (idx >> 3) & 255;
    int j = (idx >> 11) & 7;
    int s = (idx >> 14) & 15;
    int w = t >> 6, lane = t & 63, quad = lane >> 4, l16 = lane & 15;
    int kc = j >> 2, hl = (j >> 1) & 1, nt = j & 1;
    int o  = w * 32 + nt * 16 + l16;
    int kg = s * 64 + kc * 32 + quad * 8 + e;
    int i = kg >> 4, trig = (kg >> 3) & 1, h = kg & 7;
    int widx = ((trig * C_HID + o) * C_IN + i) * C_H + h;
    f16 hi, lo; split16(load_in(W, widx, is_f32), hi, lo);
    B[idx] = hl ? lo : hi;
}

__global__ void repack_mp(const void* __restrict__ W, f16* __restrict__ B,
                          const int* __restrict__ flagp) {
    const int is_f32 = *flagp;
    int idx = blockIdx.x * blockDim.x + threadIdx.x;
    if (idx >= C_L * 32 * 8 * 256 * 8) return;    // 1572864 f16
    int e = idx & 7;
    int t = (idx >> 3) & 255;
    int j = (idx >> 11) & 7;
    int s = (idx >> 14) & 31;
    int l = idx >> 19;
    int w = t >> 6, lane = t & 63, quad = lane >> 4, l16 = lane & 15;
    int kc = j >> 2, hl = (j >> 1) & 1, nt = j & 1;
    int o  = w * 32 + nt * 16 + l16;
    int kg = s * 64 + kc * 32 + quad * 8 + e;
    int i = kg >> 4, trig = (kg >> 3) & 1, h = kg & 7;
    int widx = (((l * 2 + trig) * C_HID + o) * C_HID + i) * C_H + h;
    f16 hi, lo; split16(load_in(W, widx, is_f32), hi, lo);
    B[idx] = hl ? lo : hi;
}

// readout weights stay fp32 (tiny GEMM)
__global__ void repack_read(const void* __restrict__ W, float* __restrict__ B, const int* __restrict__ flagp) {
    const int is_f32 = *flagp;
    int idx = blockIdx.x * blockDim.x + threadIdx.x;
    if (idx >= 2 * C_LAT * C_HID * C_H) return;
    int h = idx & 7; int t = idx >> 3;
    int i = t & 127; t >>= 7;
    int o = t & 31; int trig = t >> 5;
    B[(i * 16 + trig * 8 + h) * C_LAT + o] = load_in(W, idx, is_f32);
}

// ---------- graph prep ----------
// v5: csr_fill's random 4-B scatter cost 103 MB of write-allocate (16x amplification,
// 117 us). Replaced by a bucketed counting-sort placement: all scatter writes confined
// to cache-resident windows. Packed-edge path requires N <= 65536 (r,c in 16 bits);
// falls back to the old path otherwise.

__global__ void deg_count(const int* __restrict__ col, int* __restrict__ deg, int E, int N) {
    int idx = blockIdx.x * blockDim.x + threadIdx.x;
    if (idx >= E + N) return;
    int c = (idx < E) ? col[idx] : (idx - E);
    atomicAdd(&deg[c], 1);
}

// deg atomics + 512-bin bucket histogram (bucket = c>>7) in one pass over edges
__global__ __launch_bounds__(256) void deg_count_hist(const int* __restrict__ col, int* __restrict__ deg,
                                                      int* __restrict__ bhist, int E, int N) {
    __shared__ int lh[512];
    for (int i = threadIdx.x; i < 512; i += 256) lh[i] = 0;
    __syncthreads();
    int total = E + N;
    for (int idx = blockIdx.x * blockDim.x + threadIdx.x; idx < total; idx += gridDim.x * blockDim.x) {
        int c = (idx < E) ? col[idx] : (idx - E);
        atomicAdd(&deg[c], 1);
        atomicAdd(&lh[c >> 7], 1);
    }
    __syncthreads();
    for (int i = threadIdx.x; i < 512; i += 256)
        if (lh[i]) atomicAdd(&bhist[i], lh[i]);
}

// exclusive scan of <=512 bucket counts; bbase[NB] = total; bcur = running cursors
__global__ void bucket_prefix(const int* __restrict__ bhist, int* __restrict__ bbase,
                              int* __restrict__ bcur, int NB) {
    __shared__ int sd[512];
    int t = threadIdx.x;
    int v = (t < NB) ? bhist[t] : 0;
    sd[t] = v;
    __syncthreads();
    for (int off = 1; off < 512; off <<= 1) {
        int x = (t >= off) ? sd[t - off] : 0;
        __syncthreads();
        sd[t] += x;
        __syncthreads();
    }
    if (t < NB) { int e = sd[t] - v; bbase[t] = e; bcur[t] = e; }
    if (t == 511) bbase[NB] = sd[511];
}

// append packed (r<<16|c) into per-bucket dense regions: writes fill lines before eviction
__global__ __launch_bounds__(256) void bucket_scatter(const int* __restrict__ row, const int* __restrict__ col,
                                                      int* __restrict__ bcur, unsigned int* __restrict__ ebuf,
                                                      int E, int N) {
    int total = E + N;
    for (int idx = blockIdx.x * blockDim.x + threadIdx.x; idx < total; idx += gridDim.x * blockDim.x) {
        int r, c;
        if (idx < E) { r = row[idx]; c = col[idx]; } else { r = c = idx - E; }
        int pos = atomicAdd(&bcur[c >> 7], 1);
        ebuf[pos] = ((unsigned)r << 16) | (unsigned)c;
    }
}

// one block per bucket (128 nodes): per-node LDS cursors; srcs writes confined to the
// bucket's contiguous ~17 KB CSR window (L2-hot, lines fully dirtied before flush)
__global__ __launch_bounds__(256) void csr_place(const unsigned int* __restrict__ ebuf,
                                                 const int* __restrict__ bbase, const int* __restrict__ rowptr,
                                                 int* __restrict__ srcs) {
    __shared__ int lcur[128];
    int b = blockIdx.x;
    int n0 = b << 7;
    for (int i = threadIdx.x; i < 128; i += 256) lcur[i] = 0;
    __syncthreads();
    int beg = bbase[b], end = bbase[b + 1];
    for (int i = beg + threadIdx.x; i < end; i += 256) {
        unsigned e = ebuf[i];
        int c = (int)(e & 0xFFFFu);
        int r = (int)(e >> 16);
        int pos = rowptr[c] + atomicAdd(&lcur[c - n0], 1);
        srcs[pos] = r;
    }
}

__global__ void dinv_kernel(const int* __restrict__ deg, float* __restrict__ dinv, int N) {
    int n = blockIdx.x * blockDim.x + threadIdx.x;
    if (n >= N) return;
    dinv[n] = rsqrtf((float)deg[n]);   // deg >= 1 (self loop)
}

__global__ void graph_bounds(const int* __restrict__ batch, int* __restrict__ gstart, int N) {
    int g = threadIdx.x;
    if (g > C_G) return;
    int lo = 0, hi = N;
    while (lo < hi) {
        int mid = (lo + hi) >> 1;
        if (batch[mid] < g) lo = mid + 1; else hi = mid;
    }
    gstart[g] = lo;
}

// ---------- hierarchical exclusive scan of deg -> rowptr ----------
__global__ void scan1(const int* __restrict__ deg, int* __restrict__ rowptr,
                      int* __restrict__ bsum, int N) {
    __shared__ int sdata[1024];
    int i = blockIdx.x * 1024 + threadIdx.x;
    int v = (i < N) ? deg[i] : 0;
    sdata[threadIdx.x] = v;
    __syncthreads();
    for (int off = 1; off < 1024; off <<= 1) {
        int t = (threadIdx.x >= (unsigned)off) ? sdata[threadIdx.x - off] : 0;
        __syncthreads();
        sdata[threadIdx.x] += t;
        __syncthreads();
    }
    if (i < N) rowptr[i + 1] = sdata[threadIdx.x];
    if (threadIdx.x == 1023) bsum[blockIdx.x] = sdata[1023];
}

__global__ void scan2(int* __restrict__ bsum, int nb) {
    if (threadIdx.x == 0) {
        int acc = 0;
        for (int i = 0; i < nb; ++i) { int t = bsum[i]; bsum[i] = acc; acc += t; }
    }
}

__global__ void scan3(int* __restrict__ rowptr, const int* __restrict__ bsum, int N) {
    int i = blockIdx.x * 1024 + threadIdx.x;
    if (i < N) rowptr[i + 1] += bsum[blockIdx.x];
    if (i == 0) rowptr[0] = 0;
}

// fallback CSR fill (N > 65536 only)
__global__ void csr_fill(const int* __restrict__ row, const int* __restrict__ col,
                         const int* __restrict__ rowptr, int* __restrict__ cursor,
                         int* __restrict__ srcs, int E, int N) {
    int idx = blockIdx.x * blockDim.x + threadIdx.x;
    if (idx >= E + N) return;
    int r, c;
    if (idx < E) { r = row[idx]; c = col[idx]; } else { r = c = idx - E; }
    int pos = rowptr[c] + atomicAdd(&cursor[c], 1);
    srcs[pos] = r;
}

// ---------- Phi split-fp16 generation into XOR-swizzled [64][64] A-tile ----------
// Row stride 64 f16 (128 B, no pad). 16-B chunk c of row r lives at chunk (c ^ (r&7)).
__device__ inline void phi_write_split(f16* __restrict__ Ah, f16* __restrict__ Al,
                                       int offC, int offS, float x) {
    float c[8], s[8];
    __sincosf(x, &s[0], &c[0]);
#pragma unroll
    for (int h = 1; h < 8; ++h) {
        c[h] = c[h-1] * c[0] - s[h-1] * s[0];
        s[h] = s[h-1] * c[0] + c[h-1] * s[0];
    }
    f16x8 ch, cl, sh, sl;
#pragma unroll
    for (int h = 0; h < 8; ++h) {
        f16 hi, lo;
        split16(c[h], hi, lo); ch[h] = hi; cl[h] = lo;
        split16(s[h], hi, lo); sh[h] = hi; sl[h] = lo;
    }
    *(f16x8*)&Ah[offC] = ch;
    *(f16x8*)&Ah[offS] = sh;
    *(f16x8*)&Al[offC] = cl;
    *(f16x8*)&Al[offS] = sl;
}

// ---------- split-fp16 MFMA fused-Phi GEMM: Y[M,128] = Phi(X)[M, INF*16] x Bt^T ----------
// K=64 stages, 1 barrier/stage, A ping-pong in swizzled LDS, B double-buffered in
// REGISTERS from fragment-major global layout (coalesced 16B/lane, L2-resident).
#define STAGE_BODY(S, BC, BN, ACUR_H, ACUR_L, ANXT_H, ANXT_L)                         \
  {                                                                                    \
    const int s_ = (S);                                                                \
    if (s_ + 1 < NST) {                                                                \
      _Pragma("unroll")                                                                \
      for (int j = 0; j < 8; ++j)                                                      \
        BN[j] = Bf[((size_t)(s_ + 1) * 8 + j) * 256 + tid];                            \
    }                                                                                  \
    float xf_ = 0.f;                                                                   \
    if (s_ + 2 < NST && rowok)                                                         \
      xf_ = load_in(X, (size_t)gm * INF + (s_ + 2) * 4 + pf, is_f32);                  \
    if (s_ + 1 < NST)                                                                  \
      phi_write_split(ANXT_H, ANXT_L, offC, offS, xn);                                 \
    _Pragma("unroll")                                                                  \
    for (int kc = 0; kc < 2; ++kc) {                                                   \
      f16x8 ah[4], al[4];                                                              \
      _Pragma("unroll")                                                                \
      for (int mt = 0; mt < 4; ++mt) {                                                 \
        int ro = (mt * 16 + l16) * 64 + (((kc * 4 + quad) ^ (l16 & 7)) * 8);           \
        ah[mt] = *(const f16x8*)&ACUR_H[ro];                                           \
        al[mt] = *(const f16x8*)&ACUR_L[ro];                                           \
      }                                                                                \
      __builtin_amdgcn_s_setprio(1);                                                   \
      _Pragma("unroll")                                                                \
      for (int mt = 0; mt < 4; ++mt)                                                   \
        _Pragma("unroll")                                                              \
        for (int nt = 0; nt < 2; ++nt) {                                               \
          acc[mt][nt] = __builtin_amdgcn_mfma_f32_16x16x32_f16(ah[mt], BC[kc*4+nt],   acc[mt][nt], 0, 0, 0); \
          acc[mt][nt] = __builtin_amdgcn_mfma_f32_16x16x32_f16(ah[mt], BC[kc*4+2+nt], acc[mt][nt], 0, 0, 0); \
          acc[mt][nt] = __builtin_amdgcn_mfma_f32_16x16x32_f16(al[mt], BC[kc*4+nt],   acc[mt][nt], 0, 0, 0); \
        }                                                                              \
      __builtin_amdgcn_s_setprio(0);                                                   \
    }                                                                                  \
    __syncthreads();                                                                   \
    xn = xf_;                                                                          \
  }

template<int INF, bool F16OUT>
__global__ __launch_bounds__(256, 3) void kan_gemm_mfma(const void* __restrict__ X,
                                                        const f16* __restrict__ Bt,
                                                        float* __restrict__ Yf, f16* __restrict__ Yh,
                                                        const float* __restrict__ dinv,
                                                        int M, const int* __restrict__ flagp) {
    constexpr int NST = INF / 4;     // stages of K=64 (4 input features each)
    __shared__ f16 AhB[2][64 * 64];
    __shared__ f16 AlB[2][64 * 64];
    __shared__ float dinvs[64];
    const int is_f32 = flagp ? *flagp : 1;
    const int tid  = threadIdx.x;
    const int m0   = blockIdx.x * 64;
    const int w    = tid >> 6, lane = tid & 63;
    const int quad = lane >> 4, l16 = lane & 15;

    // phi role: thread owns (row = lane, feature = w) each stage
    const int pf   = w;
    const int gm   = m0 + lane;
    const bool rowok = gm < M;
    const int offC = lane * 64 + (((w * 2)     ^ (lane & 7)) * 8);
    const int offS = lane * 64 + (((w * 2 + 1) ^ (lane & 7)) * 8);

    if (F16OUT && tid < 64) dinvs[tid] = (m0 + tid < M) ? dinv[m0 + tid] : 0.f;

    f32x4 acc[4][2] = {};
    const f16x8* __restrict__ Bf = (const f16x8*)Bt;

    f16x8 b0[8], b1[8];
#pragma unroll
    for (int j = 0; j < 8; ++j) b0[j] = Bf[(size_t)j * 256 + tid];

    float x0 = rowok ? load_in(X, (size_t)gm * INF + pf, is_f32) : 0.f;
    float xn = (NST > 1 && rowok) ? load_in(X, (size_t)gm * INF + 4 + pf, is_f32) : 0.f;

    phi_write_split(AhB[0], AlB[0], offC, offS, x0);
    __syncthreads();

    for (int s = 0; s < NST; s += 2) {
        STAGE_BODY(s,     b0, b1, AhB[0], AlB[0], AhB[1], AlB[1]);
        STAGE_BODY(s + 1, b1, b0, AhB[1], AlB[1], AhB[0], AlB[0]);
    }

    // C/D layout: col = lane&15, row = quad*4 + reg
#pragma unroll
    for (int mt = 0; mt < 4; ++mt) {
        int rloc = mt * 16 + quad * 4;
#pragma unroll
        for (int nt = 0; nt < 2; ++nt) {
            int cn = w * 32 + nt * 16 + l16;
#pragma unroll
            for (int r = 0; r < 4; ++r) {
                int m = m0 + rloc + r;
                if (m < M) {
                    if (F16OUT) Yh[(size_t)m * 128 + cn] = (f16)(acc[mt][nt][r] * dinvs[rloc + r]);
                    else        Yf[(size_t)m * 128 + cn] = acc[mt][nt][r];
                }
            }
        }
    }
}

// ---------- CSR aggregation: one wave per dest, shuffled src staging + 4-deep gather ----------
__global__ __launch_bounds__(256) void aggregate(const f16* __restrict__ Hin, float* __restrict__ Hout,
                                                 const int* __restrict__ rowptr, const int* __restrict__ srcs,
                                                 const float* __restrict__ dinv, int N) {
    int wave = (int)((blockIdx.x * blockDim.x + threadIdx.x) >> 6);
    int lane = threadIdx.x & 63;
    if (wave >= N) return;
    const f16x2* H2 = (const f16x2*)Hin;
    int beg = rowptr[wave], end = rowptr[wave + 1];
    float2 a0 = {0.f, 0.f}, a1 = {0.f, 0.f};
    int j = beg;
    while (j < end) {
        int cnt = end - j; if (cnt > 64) cnt = 64;
        int sv = (lane < cnt) ? srcs[j + lane] : 0;
        int t = 0;
        for (; t + 4 <= cnt; t += 4) {
            int s0 = __shfl(sv, t + 0);
            int s1 = __shfl(sv, t + 1);
            int s2 = __shfl(sv, t + 2);
            int s3 = __shfl(sv, t + 3);
            f16x2 h0 = H2[(size_t)s0 * 64 + lane];
            f16x2 h1 = H2[(size_t)s1 * 64 + lane];
            f16x2 h2 = H2[(size_t)s2 * 64 + lane];
            f16x2 h3 = H2[(size_t)s3 * 64 + lane];
            a0.x += (float)h0[0] + (float)h1[0];
            a0.y += (float)h0[1] + (float)h1[1];
            a1.x += (float)h2[0] + (float)h3[0];
            a1.y += (float)h2[1] + (float)h3[1];
        }
        for (; t < cnt; ++t) {
            int s0 = __shfl(sv, t);
            f16x2 h0 = H2[(size_t)s0 * 64 + lane];
            a0.x += (float)h0[0];
            a0.y += (float)h0[1];
        }
        j += cnt;
    }
    float dv = dinv[wave];
    float2 acc = {(a0.x + a1.x) * dv, (a0.y + a1.y) * dv};
    ((float2*)Hout)[(size_t)wave * 64 + lane] = acc;
}

// ---------- fused mean-pool + readout ----------
__global__ __launch_bounds__(256) void pool_readout(const float* __restrict__ H, const int* __restrict__ gstart,
                                                    const float* __restrict__ B, void* __restrict__ out,
                                                    const int* __restrict__ flagp) {
    __shared__ float phi[2048];
    __shared__ float red[256];
    __shared__ float part[8][32];
    const int is_f32 = *flagp;
    int g = blockIdx.x;
    int tid = threadIdx.x;
    int s0 = gstart[g], e0 = gstart[g + 1];
    int f = tid & 127, half = tid >> 7;
    float sum = 0.f;
    for (int n = s0 + half; n < e0; n += 2)
        sum += H[(size_t)n * C_HID + f];
    red[tid] = sum;
    __syncthreads();
    if (tid < 128) {
        float cnt = fmaxf((float)(e0 - s0), 1.0f);
        float x = (red[tid] + red[tid + 128]) / cnt;
        float s1, c1;
        __sincosf(x, &s1, &c1);
        phi[tid * 16 + 0] = c1; phi[tid * 16 + 8] = s1;
        float ck = c1, sk = s1;
#pragma unroll
        for (int h = 1; h < 8; ++h) {
            float cn = ck * c1 - sk * s1;
            float sn = sk * c1 + ck * s1;
            phi[tid * 16 + h] = cn; phi[tid * 16 + 8 + h] = sn;
            ck = cn; sk = sn;
        }
    }
    __syncthreads();
    int o = tid & 31, p = tid >> 5;
    float acc = 0.f;
    for (int k = p * 256; k < p * 256 + 256; ++k)
        acc = fmaf(phi[k], B[k * C_LAT + o], acc);
    part[p][o] = acc;
    __syncthreads();
    if (tid < 32) {
        float s = 0.f;
#pragma unroll
        for (int pp = 0; pp < 8; ++pp) s += part[pp][tid];
        if (is_f32) ((float*)out)[g * C_LAT + tid] = s;
        else        ((bf16*)out)[g * C_LAT + tid] = __float2bfloat16(s);
    }
}

extern "C" void kernel_launch(void* const* d_in, const int* in_sizes, int n_in,
                              void* d_out, int out_size, void* d_ws, size_t ws_size,
                              hipStream_t stream) {
    const void* features = d_in[0];
    const int*  edge     = (const int*)d_in[1];
    const int*  batch    = (const int*)d_in[2];
    const void* W_embed  = d_in[3];
    const void* W_mp     = d_in[4];
    const void* W_read   = d_in[5];

    const int N = in_sizes[0] / C_IN;
    const int E = in_sizes[1] / 2;
    const int* row = edge;
    const int* col = edge + E;
    const int nScanBlocks = (N + 1023) / 1024;
    const int NB = (N + 127) >> 7;           // buckets of 128 nodes
    const bool packed_ok = (N <= 65536) && (NB <= 512);

    char* ws = (char*)d_ws;
    auto alloc = [&](size_t bytes) { char* p = ws; ws += (bytes + 255) & ~(size_t)255; return p; };
    float* h_a    = (float*)alloc((size_t)N * C_HID * 4);
    f16*   h16    = (f16*)alloc((size_t)N * C_HID * 2);
    f16*   Bte    = (f16*)alloc((size_t)16 * 8 * 256 * 8 * 2);          // 512 KB
    f16*   Btmp   = (f16*)alloc((size_t)C_L * 32 * 8 * 256 * 8 * 2);    // 3 MB
    float* Brd    = (float*)alloc((size_t)2048 * C_LAT * 4);
    int*   deg    = (int*)alloc((size_t)N * 4);
    float* dinv   = (float*)alloc((size_t)N * 4);
    int*   rowptr = (int*)alloc((size_t)(N + 1) * 4);
    int*   cursor = (int*)alloc((size_t)N * 4);
    int*   srcs   = (int*)alloc((size_t)(E + N) * 4);
    int*   bsum   = (int*)alloc((size_t)nScanBlocks * 4);
    int*   gstart = (int*)alloc((size_t)(C_G + 1) * 4);
    int*   dflag  = (int*)alloc(256);
    int*   bhist  = (int*)alloc(512 * 4);
    int*   bbase  = (int*)alloc(513 * 4);
    int*   bcur   = (int*)alloc(512 * 4);
    unsigned int* ebuf = (unsigned int*)alloc((size_t)(E + N) * 4);

    hipMemsetAsync(deg, 0, (size_t)N * 4, stream);

    detect_dtype<<<1, 256, 0, stream>>>((const unsigned short*)W_embed, dflag);

    repack_embed<<<(16 * 8 * 256 * 8 + 255) / 256, 256, 0, stream>>>(W_embed, Bte, dflag);
    repack_mp<<<(C_L * 32 * 8 * 256 * 8 + 255) / 256, 256, 0, stream>>>(W_mp, Btmp, dflag);
    repack_read<<<(2 * C_LAT * C_HID * C_H + 255) / 256, 256, 0, stream>>>(W_read, Brd, dflag);

    if (packed_ok) {
        hipMemsetAsync(bhist, 0, 512 * 4, stream);
        deg_count_hist<<<1024, 256, 0, stream>>>(col, deg, bhist, E, N);
    } else {
        hipMemsetAsync(cursor, 0, (size_t)N * 4, stream);
        deg_count<<<(E + N + 255) / 256, 256, 0, stream>>>(col, deg, E, N);
    }
    dinv_kernel<<<(N + 255) / 256, 256, 0, stream>>>(deg, dinv, N);
    graph_bounds<<<1, 128, 0, stream>>>(batch, gstart, N);
    scan1<<<nScanBlocks, 1024, 0, stream>>>(deg, rowptr, bsum, N);
    scan2<<<1, 64, 0, stream>>>(bsum, nScanBlocks);
    scan3<<<nScanBlocks, 1024, 0, stream>>>(rowptr, bsum, N);
    if (packed_ok) {
        bucket_prefix<<<1, 512, 0, stream>>>(bhist, bbase, bcur, NB);
        bucket_scatter<<<1024, 256, 0, stream>>>(row, col, bcur, ebuf, E, N);
        csr_place<<<NB, 256, 0, stream>>>(ebuf, bbase, rowptr, srcs);
    } else {
        csr_fill<<<(E + N + 255) / 256, 256, 0, stream>>>(row, col, rowptr, cursor, srcs, E, N);
    }

    const int gemm_grid = (N + 63) / 64;
    kan_gemm_mfma<C_IN, false><<<gemm_grid, 256, 0, stream>>>(features, Bte, h_a, nullptr, nullptr, N, dflag);
    for (int l = 0; l < C_L; ++l) {
        kan_gemm_mfma<C_HID, true><<<gemm_grid, 256, 0, stream>>>(h_a, Btmp + (size_t)l * 32 * 8 * 256 * 8,
                                                                  nullptr, h16, dinv, N, nullptr);
        aggregate<<<((size_t)N * 64 + 255) / 256, 256, 0, stream>>>(h16, h_a, rowptr, srcs, dinv, N);
    }

    pool_readout<<<C_G, 256, 0, stream>>>(h_a, gstart, Brd, d_out, dflag);
}

// Round 5
// 894.216 us; speedup vs baseline: 1.6092x; 1.6092x over previous
//
#include <hip/hip_runtime.h>
#include <hip/hip_bf16.h>
#include <cstdint>

typedef __hip_bfloat16 bf16;
typedef _Float16 f16;
typedef f16 f16x2 __attribute__((ext_vector_type(2)));
typedef f16 f16x8 __attribute__((ext_vector_type(8)));
typedef float f32x4 __attribute__((ext_vector_type(4)));

#define C_IN   64
#define C_HID  128
#define C_LAT  32
#define C_H    8
#define C_L    3
#define C_G    64

// Runtime input-dtype handling (harness may hand fp32 or bf16). flag==1 -> fp32.
__device__ inline float load_in(const void* p, size_t idx, int is_f32) {
    if (is_f32) return ((const float*)p)[idx];
    return __bfloat162float(((const bf16*)p)[idx]);
}

__global__ void detect_dtype(const unsigned short* __restrict__ W, int* __restrict__ flag) {
    __shared__ int cnt;
    if (threadIdx.x == 0) cnt = 0;
    __syncthreads();
    int local = 0;
    for (int i = threadIdx.x; i < 8192; i += 256) {
        int e = (W[i] >> 7) & 0xFF;
        if (e >= 135) local++;
    }
    atomicAdd(&cnt, local);
    __syncthreads();
    if (threadIdx.x == 0) *flag = (cnt > 64) ? 1 : 0;
}

__device__ inline void split16(float v, f16& hi, f16& lo) {
    hi = (f16)v;
    lo = (f16)(v - (float)hi);
}

// ---------- weight repack -> fragment-major split-f16 layout ----------
// B[((s*8 + j)*256 + t)*8 + e], j = kc*4 + hl*2 + nt
// frag(j,t): o = w*32 + nt*16 + l16;  kglob = s*64 + kc*32 + quad*8 + e
__global__ void repack_embed(const void* __restrict__ W, f16* __restrict__ B,
                             const int* __restrict__ flagp) {
    const int is_f32 = *flagp;
    int idx = blockIdx.x * blockDim.x + threadIdx.x;
    if (idx >= 16 * 8 * 256 * 8) return;          // 262144 f16
    int e = idx & 7;
    int t = (idx >> 3) & 255;
    int j = (idx >> 11) & 7;
    int s = (idx >> 14) & 15;
    int w = t >> 6, lane = t & 63, quad = lane >> 4, l16 = lane & 15;
    int kc = j >> 2, hl = (j >> 1) & 1, nt = j & 1;
    int o  = w * 32 + nt * 16 + l16;
    int kg = s * 64 + kc * 32 + quad * 8 + e;
    int i = kg >> 4, trig = (kg >> 3) & 1, h = kg & 7;
    int widx = ((trig * C_HID + o) * C_IN + i) * C_H + h;
    f16 hi, lo; split16(load_in(W, widx, is_f32), hi, lo);
    B[idx] = hl ? lo : hi;
}

__global__ void repack_mp(const void* __restrict__ W, f16* __restrict__ B,
                          const int* __restrict__ flagp) {
    const int is_f32 = *flagp;
    int idx = blockIdx.x * blockDim.x + threadIdx.x;
    if (idx >= C_L * 32 * 8 * 256 * 8) return;    // 1572864 f16
    int e = idx & 7;
    int t = (idx >> 3) & 255;
    int j = (idx >> 11) & 7;
    int s = (idx >> 14) & 31;
    int l = idx >> 19;
    int w = t >> 6, lane = t & 63, quad = lane >> 4, l16 = lane & 15;
    int kc = j >> 2, hl = (j >> 1) & 1, nt = j & 1;
    int o  = w * 32 + nt * 16 + l16;
    int kg = s * 64 + kc * 32 + quad * 8 + e;
    int i = kg >> 4, trig = (kg >> 3) & 1, h = kg & 7;
    int widx = (((l * 2 + trig) * C_HID + o) * C_HID + i) * C_H + h;
    f16 hi, lo; split16(load_in(W, widx, is_f32), hi, lo);
    B[idx] = hl ? lo : hi;
}

// readout weights stay fp32 (tiny GEMM)
__global__ void repack_read(const void* __restrict__ W, float* __restrict__ B, const int* __restrict__ flagp) {
    const int is_f32 = *flagp;
    int idx = blockIdx.x * blockDim.x + threadIdx.x;
    if (idx >= 2 * C_LAT * C_HID * C_H) return;
    int h = idx & 7; int t = idx >> 3;
    int i = t & 127; t >>= 7;
    int o = t & 31; int trig = t >> 5;
    B[(i * 16 + trig * 8 + h) * C_LAT + o] = load_in(W, idx, is_f32);
}

// ---------- graph prep (v4 path restored: bucketed counting-sort was 5x worse — 1.65M
// atomics on ~25 cache lines serialize, and scattered sub-line stores keep ~10x HBM
// write amplification regardless of bucket density. csr_fill's 117us is the known cost.)
__global__ void deg_count(const int* __restrict__ col, int* __restrict__ deg, int E, int N) {
    int idx = blockIdx.x * blockDim.x + threadIdx.x;
    if (idx >= E + N) return;
    int c = (idx < E) ? col[idx] : (idx - E);
    atomicAdd(&deg[c], 1);
}

__global__ void dinv_kernel(const int* __restrict__ deg, float* __restrict__ dinv, int N) {
    int n = blockIdx.x * blockDim.x + threadIdx.x;
    if (n >= N) return;
    dinv[n] = rsqrtf((float)deg[n]);   // deg >= 1 (self loop)
}

__global__ void graph_bounds(const int* __restrict__ batch, int* __restrict__ gstart, int N) {
    int g = threadIdx.x;
    if (g > C_G) return;
    int lo = 0, hi = N;
    while (lo < hi) {
        int mid = (lo + hi) >> 1;
        if (batch[mid] < g) lo = mid + 1; else hi = mid;
    }
    gstart[g] = lo;
}

// ---------- hierarchical exclusive scan of deg -> rowptr ----------
__global__ void scan1(const int* __restrict__ deg, int* __restrict__ rowptr,
                      int* __restrict__ bsum, int N) {
    __shared__ int sdata[1024];
    int i = blockIdx.x * 1024 + threadIdx.x;
    int v = (i < N) ? deg[i] : 0;
    sdata[threadIdx.x] = v;
    __syncthreads();
    for (int off = 1; off < 1024; off <<= 1) {
        int t = (threadIdx.x >= (unsigned)off) ? sdata[threadIdx.x - off] : 0;
        __syncthreads();
        sdata[threadIdx.x] += t;
        __syncthreads();
    }
    if (i < N) rowptr[i + 1] = sdata[threadIdx.x];
    if (threadIdx.x == 1023) bsum[blockIdx.x] = sdata[1023];
}

__global__ void scan2(int* __restrict__ bsum, int nb) {
    if (threadIdx.x == 0) {
        int acc = 0;
        for (int i = 0; i < nb; ++i) { int t = bsum[i]; bsum[i] = acc; acc += t; }
    }
}

__global__ void scan3(int* __restrict__ rowptr, const int* __restrict__ bsum, int N) {
    int i = blockIdx.x * 1024 + threadIdx.x;
    if (i < N) rowptr[i + 1] += bsum[blockIdx.x];
    if (i == 0) rowptr[0] = 0;
}

__global__ void csr_fill(const int* __restrict__ row, const int* __restrict__ col,
                         const int* __restrict__ rowptr, int* __restrict__ cursor,
                         int* __restrict__ srcs, int E, int N) {
    int idx = blockIdx.x * blockDim.x + threadIdx.x;
    if (idx >= E + N) return;
    int r, c;
    if (idx < E) { r = row[idx]; c = col[idx]; } else { r = c = idx - E; }
    int pos = rowptr[c] + atomicAdd(&cursor[c], 1);
    srcs[pos] = r;
}

// ---------- Phi split-fp16 generation into XOR-swizzled [64][64] A-tile ----------
// Row stride 64 f16 (128 B, no pad). 16-B chunk c of row r lives at chunk (c ^ (r&7)).
__device__ inline void phi_write_split(f16* __restrict__ Ah, f16* __restrict__ Al,
                                       int offC, int offS, float x) {
    float c[8], s[8];
    __sincosf(x, &s[0], &c[0]);
#pragma unroll
    for (int h = 1; h < 8; ++h) {
        c[h] = c[h-1] * c[0] - s[h-1] * s[0];
        s[h] = s[h-1] * c[0] + c[h-1] * s[0];
    }
    f16x8 ch, cl, sh, sl;
#pragma unroll
    for (int h = 0; h < 8; ++h) {
        f16 hi, lo;
        split16(c[h], hi, lo); ch[h] = hi; cl[h] = lo;
        split16(s[h], hi, lo); sh[h] = hi; sl[h] = lo;
    }
    *(f16x8*)&Ah[offC] = ch;
    *(f16x8*)&Ah[offS] = sh;
    *(f16x8*)&Al[offC] = cl;
    *(f16x8*)&Al[offS] = sl;
}

// ---------- split-fp16 MFMA fused-Phi GEMM: Y[M,128] = Phi(X)[M, INF*16] x Bt^T ----------
// K=64 stages, 1 barrier/stage, A ping-pong in swizzled LDS, B double-buffered in
// REGISTERS from fragment-major global layout (coalesced 16B/lane, L2-resident).
#define STAGE_BODY(S, BC, BN, ACUR_H, ACUR_L, ANXT_H, ANXT_L)                         \
  {                                                                                    \
    const int s_ = (S);                                                                \
    if (s_ + 1 < NST) {                                                                \
      _Pragma("unroll")                                                                \
      for (int j = 0; j < 8; ++j)                                                      \
        BN[j] = Bf[((size_t)(s_ + 1) * 8 + j) * 256 + tid];                            \
    }                                                                                  \
    float xf_ = 0.f;                                                                   \
    if (s_ + 2 < NST && rowok)                                                         \
      xf_ = load_in(X, (size_t)gm * INF + (s_ + 2) * 4 + pf, is_f32);                  \
    if (s_ + 1 < NST)                                                                  \
      phi_write_split(ANXT_H, ANXT_L, offC, offS, xn);                                 \
    _Pragma("unroll")                                                                  \
    for (int kc = 0; kc < 2; ++kc) {                                                   \
      f16x8 ah[4], al[4];                                                              \
      _Pragma("unroll")                                                                \
      for (int mt = 0; mt < 4; ++mt) {                                                 \
        int ro = (mt * 16 + l16) * 64 + (((kc * 4 + quad) ^ (l16 & 7)) * 8);           \
        ah[mt] = *(const f16x8*)&ACUR_H[ro];                                           \
        al[mt] = *(const f16x8*)&ACUR_L[ro];                                           \
      }                                                                                \
      __builtin_amdgcn_s_setprio(1);                                                   \
      _Pragma("unroll")                                                                \
      for (int mt = 0; mt < 4; ++mt)                                                   \
        _Pragma("unroll")                                                              \
        for (int nt = 0; nt < 2; ++nt) {                                               \
          acc[mt][nt] = __builtin_amdgcn_mfma_f32_16x16x32_f16(ah[mt], BC[kc*4+nt],   acc[mt][nt], 0, 0, 0); \
          acc[mt][nt] = __builtin_amdgcn_mfma_f32_16x16x32_f16(ah[mt], BC[kc*4+2+nt], acc[mt][nt], 0, 0, 0); \
          acc[mt][nt] = __builtin_amdgcn_mfma_f32_16x16x32_f16(al[mt], BC[kc*4+nt],   acc[mt][nt], 0, 0, 0); \
        }                                                                              \
      __builtin_amdgcn_s_setprio(0);                                                   \
    }                                                                                  \
    __syncthreads();                                                                   \
    xn = xf_;                                                                          \
  }

template<int INF, bool F16OUT>
__global__ __launch_bounds__(256, 3) void kan_gemm_mfma(const void* __restrict__ X,
                                                        const f16* __restrict__ Bt,
                                                        float* __restrict__ Yf, f16* __restrict__ Yh,
                                                        const float* __restrict__ dinv,
                                                        int M, const int* __restrict__ flagp) {
    constexpr int NST = INF / 4;     // stages of K=64 (4 input features each)
    __shared__ f16 AhB[2][64 * 64];
    __shared__ f16 AlB[2][64 * 64];
    __shared__ float dinvs[64];
    const int is_f32 = flagp ? *flagp : 1;
    const int tid  = threadIdx.x;
    const int m0   = blockIdx.x * 64;
    const int w    = tid >> 6, lane = tid & 63;
    const int quad = lane >> 4, l16 = lane & 15;

    // phi role: thread owns (row = lane, feature = w) each stage
    const int pf   = w;
    const int gm   = m0 + lane;
    const bool rowok = gm < M;
    const int offC = lane * 64 + (((w * 2)     ^ (lane & 7)) * 8);
    const int offS = lane * 64 + (((w * 2 + 1) ^ (lane & 7)) * 8);

    if (F16OUT && tid < 64) dinvs[tid] = (m0 + tid < M) ? dinv[m0 + tid] : 0.f;

    f32x4 acc[4][2] = {};
    const f16x8* __restrict__ Bf = (const f16x8*)Bt;

    f16x8 b0[8], b1[8];
#pragma unroll
    for (int j = 0; j < 8; ++j) b0[j] = Bf[(size_t)j * 256 + tid];

    float x0 = rowok ? load_in(X, (size_t)gm * INF + pf, is_f32) : 0.f;
    float xn = (NST > 1 && rowok) ? load_in(X, (size_t)gm * INF + 4 + pf, is_f32) : 0.f;

    phi_write_split(AhB[0], AlB[0], offC, offS, x0);
    __syncthreads();

    for (int s = 0; s < NST; s += 2) {
        STAGE_BODY(s,     b0, b1, AhB[0], AlB[0], AhB[1], AlB[1]);
        STAGE_BODY(s + 1, b1, b0, AhB[1], AlB[1], AhB[0], AlB[0]);
    }

    // C/D layout: col = lane&15, row = quad*4 + reg
#pragma unroll
    for (int mt = 0; mt < 4; ++mt) {
        int rloc = mt * 16 + quad * 4;
#pragma unroll
        for (int nt = 0; nt < 2; ++nt) {
            int cn = w * 32 + nt * 16 + l16;
#pragma unroll
            for (int r = 0; r < 4; ++r) {
                int m = m0 + rloc + r;
                if (m < M) {
                    if (F16OUT) Yh[(size_t)m * 128 + cn] = (f16)(acc[mt][nt][r] * dinvs[rloc + r]);
                    else        Yf[(size_t)m * 128 + cn] = acc[mt][nt][r];
                }
            }
        }
    }
}

// ---------- CSR aggregation: one wave per dest, 8-deep gather ILP ----------
// r0 counters: VALUBusy 5.7%, HBM ~0, Occupancy 11.6% -> latency-bound with only 4
// rows (1 KB) in flight. 8-deep doubles per-wave MLP at +8 VGPR (16 -> ~24, still
// far from any occupancy cliff).
__global__ __launch_bounds__(256) void aggregate(const f16* __restrict__ Hin, float* __restrict__ Hout,
                                                 const int* __restrict__ rowptr, const int* __restrict__ srcs,
                                                 const float* __restrict__ dinv, int N) {
    int wave = (int)((blockIdx.x * blockDim.x + threadIdx.x) >> 6);
    int lane = threadIdx.x & 63;
    if (wave >= N) return;
    const f16x2* H2 = (const f16x2*)Hin;
    int beg = rowptr[wave], end = rowptr[wave + 1];
    float2 a0 = {0.f, 0.f}, a1 = {0.f, 0.f}, a2 = {0.f, 0.f}, a3 = {0.f, 0.f};
    int j = beg;
    while (j < end) {
        int cnt = end - j; if (cnt > 64) cnt = 64;
        int sv = (lane < cnt) ? srcs[j + lane] : 0;
        int t = 0;
        for (; t + 8 <= cnt; t += 8) {
            int s0 = __shfl(sv, t + 0);
            int s1 = __shfl(sv, t + 1);
            int s2 = __shfl(sv, t + 2);
            int s3 = __shfl(sv, t + 3);
            int s4 = __shfl(sv, t + 4);
            int s5 = __shfl(sv, t + 5);
            int s6 = __shfl(sv, t + 6);
            int s7 = __shfl(sv, t + 7);
            // 8 independent row-gathers in flight
            f16x2 h0 = H2[(size_t)s0 * 64 + lane];
            f16x2 h1 = H2[(size_t)s1 * 64 + lane];
            f16x2 h2 = H2[(size_t)s2 * 64 + lane];
            f16x2 h3 = H2[(size_t)s3 * 64 + lane];
            f16x2 h4 = H2[(size_t)s4 * 64 + lane];
            f16x2 h5 = H2[(size_t)s5 * 64 + lane];
            f16x2 h6 = H2[(size_t)s6 * 64 + lane];
            f16x2 h7 = H2[(size_t)s7 * 64 + lane];
            a0.x += (float)h0[0] + (float)h1[0];
            a0.y += (float)h0[1] + (float)h1[1];
            a1.x += (float)h2[0] + (float)h3[0];
            a1.y += (float)h2[1] + (float)h3[1];
            a2.x += (float)h4[0] + (float)h5[0];
            a2.y += (float)h4[1] + (float)h5[1];
            a3.x += (float)h6[0] + (float)h7[0];
            a3.y += (float)h6[1] + (float)h7[1];
        }
        for (; t < cnt; ++t) {
            int s0 = __shfl(sv, t);
            f16x2 h0 = H2[(size_t)s0 * 64 + lane];
            a0.x += (float)h0[0];
            a0.y += (float)h0[1];
        }
        j += cnt;
    }
    float dv = dinv[wave];
    float2 acc = {(a0.x + a1.x + a2.x + a3.x) * dv, (a0.y + a1.y + a2.y + a3.y) * dv};
    ((float2*)Hout)[(size_t)wave * 64 + lane] = acc;
}

// ---------- fused mean-pool + readout ----------
__global__ __launch_bounds__(256) void pool_readout(const float* __restrict__ H, const int* __restrict__ gstart,
                                                    const float* __restrict__ B, void* __restrict__ out,
                                                    const int* __restrict__ flagp) {
    __shared__ float phi[2048];
    __shared__ float red[256];
    __shared__ float part[8][32];
    const int is_f32 = *flagp;
    int g = blockIdx.x;
    int tid = threadIdx.x;
    int s0 = gstart[g], e0 = gstart[g + 1];
    int f = tid & 127, half = tid >> 7;
    float sum = 0.f;
    for (int n = s0 + half; n < e0; n += 2)
        sum += H[(size_t)n * C_HID + f];
    red[tid] = sum;
    __syncthreads();
    if (tid < 128) {
        float cnt = fmaxf((float)(e0 - s0), 1.0f);
        float x = (red[tid] + red[tid + 128]) / cnt;
        float s1, c1;
        __sincosf(x, &s1, &c1);
        phi[tid * 16 + 0] = c1; phi[tid * 16 + 8] = s1;
        float ck = c1, sk = s1;
#pragma unroll
        for (int h = 1; h < 8; ++h) {
            float cn = ck * c1 - sk * s1;
            float sn = sk * c1 + ck * s1;
            phi[tid * 16 + h] = cn; phi[tid * 16 + 8 + h] = sn;
            ck = cn; sk = sn;
        }
    }
    __syncthreads();
    int o = tid & 31, p = tid >> 5;
    float acc = 0.f;
    for (int k = p * 256; k < p * 256 + 256; ++k)
        acc = fmaf(phi[k], B[k * C_LAT + o], acc);
    part[p][o] = acc;
    __syncthreads();
    if (tid < 32) {
        float s = 0.f;
#pragma unroll
        for (int pp = 0; pp < 8; ++pp) s += part[pp][tid];
        if (is_f32) ((float*)out)[g * C_LAT + tid] = s;
        else        ((bf16*)out)[g * C_LAT + tid] = __float2bfloat16(s);
    }
}

extern "C" void kernel_launch(void* const* d_in, const int* in_sizes, int n_in,
                              void* d_out, int out_size, void* d_ws, size_t ws_size,
                              hipStream_t stream) {
    const void* features = d_in[0];
    const int*  edge     = (const int*)d_in[1];
    const int*  batch    = (const int*)d_in[2];
    const void* W_embed  = d_in[3];
    const void* W_mp     = d_in[4];
    const void* W_read   = d_in[5];

    const int N = in_sizes[0] / C_IN;
    const int E = in_sizes[1] / 2;
    const int* row = edge;
    const int* col = edge + E;
    const int nScanBlocks = (N + 1023) / 1024;

    char* ws = (char*)d_ws;
    auto alloc = [&](size_t bytes) { char* p = ws; ws += (bytes + 255) & ~(size_t)255; return p; };
    float* h_a    = (float*)alloc((size_t)N * C_HID * 4);
    f16*   h16    = (f16*)alloc((size_t)N * C_HID * 2);
    f16*   Bte    = (f16*)alloc((size_t)16 * 8 * 256 * 8 * 2);          // 512 KB
    f16*   Btmp   = (f16*)alloc((size_t)C_L * 32 * 8 * 256 * 8 * 2);    // 3 MB
    float* Brd    = (float*)alloc((size_t)2048 * C_LAT * 4);
    int*   deg    = (int*)alloc((size_t)N * 4);
    float* dinv   = (float*)alloc((size_t)N * 4);
    int*   rowptr = (int*)alloc((size_t)(N + 1) * 4);
    int*   cursor = (int*)alloc((size_t)N * 4);
    int*   srcs   = (int*)alloc((size_t)(E + N) * 4);
    int*   bsum   = (int*)alloc((size_t)nScanBlocks * 4);
    int*   gstart = (int*)alloc((size_t)(C_G + 1) * 4);
    int*   dflag  = (int*)alloc(256);

    hipMemsetAsync(deg, 0, (size_t)N * 4, stream);
    hipMemsetAsync(cursor, 0, (size_t)N * 4, stream);

    detect_dtype<<<1, 256, 0, stream>>>((const unsigned short*)W_embed, dflag);

    repack_embed<<<(16 * 8 * 256 * 8 + 255) / 256, 256, 0, stream>>>(W_embed, Bte, dflag);
    repack_mp<<<(C_L * 32 * 8 * 256 * 8 + 255) / 256, 256, 0, stream>>>(W_mp, Btmp, dflag);
    repack_read<<<(2 * C_LAT * C_HID * C_H + 255) / 256, 256, 0, stream>>>(W_read, Brd, dflag);

    deg_count<<<(E + N + 255) / 256, 256, 0, stream>>>(col, deg, E, N);
    dinv_kernel<<<(N + 255) / 256, 256, 0, stream>>>(deg, dinv, N);
    graph_bounds<<<1, 128, 0, stream>>>(batch, gstart, N);
    scan1<<<nScanBlocks, 1024, 0, stream>>>(deg, rowptr, bsum, N);
    scan2<<<1, 64, 0, stream>>>(bsum, nScanBlocks);
    scan3<<<nScanBlocks, 1024, 0, stream>>>(rowptr, bsum, N);
    csr_fill<<<(E + N + 255) / 256, 256, 0, stream>>>(row, col, rowptr, cursor, srcs, E, N);

    const int gemm_grid = (N + 63) / 64;
    kan_gemm_mfma<C_IN, false><<<gemm_grid, 256, 0, stream>>>(features, Bte, h_a, nullptr, nullptr, N, dflag);
    for (int l = 0; l < C_L; ++l) {
        kan_gemm_mfma<C_HID, true><<<gemm_grid, 256, 0, stream>>>(h_a, Btmp + (size_t)l * 32 * 8 * 256 * 8,
                                                                  nullptr, h16, dinv, N, nullptr);
        aggregate<<<((size_t)N * 64 + 255) / 256, 256, 0, stream>>>(h16, h_a, rowptr, srcs, dinv, N);
    }

    pool_readout<<<C_G, 256, 0, stream>>>(h_a, gstart, Brd, d_out, dflag);
}

// Round 6
// 808.679 us; speedup vs baseline: 1.7794x; 1.1058x over previous
//
#include <hip/hip_runtime.h>
#include <hip/hip_bf16.h>
#include <cstdint>

typedef __hip_bfloat16 bf16;
typedef _Float16 f16;
typedef f16 f16x2 __attribute__((ext_vector_type(2)));
typedef f16 f16x8 __attribute__((ext_vector_type(8)));
typedef float f32x4 __attribute__((ext_vector_type(4)));

#define C_IN   64
#define C_HID  128
#define C_LAT  32
#define C_H    8
#define C_L    3
#define C_G    64

// Runtime input-dtype handling (harness may hand fp32 or bf16). flag==1 -> fp32.
__device__ inline float load_in(const void* p, size_t idx, int is_f32) {
    if (is_f32) return ((const float*)p)[idx];
    return __bfloat162float(((const bf16*)p)[idx]);
}

__global__ void detect_dtype(const unsigned short* __restrict__ W, int* __restrict__ flag) {
    __shared__ int cnt;
    if (threadIdx.x == 0) cnt = 0;
    __syncthreads();
    int local = 0;
    for (int i = threadIdx.x; i < 8192; i += 256) {
        int e = (W[i] >> 7) & 0xFF;
        if (e >= 135) local++;
    }
    atomicAdd(&cnt, local);
    __syncthreads();
    if (threadIdx.x == 0) *flag = (cnt > 64) ? 1 : 0;
}

__device__ inline void split16(float v, f16& hi, f16& lo) {
    hi = (f16)v;
    lo = (f16)(v - (float)hi);
}

// ---------- weight repack -> fragment-major split-f16 layout ----------
// B[((s*8 + j)*256 + t)*8 + e], j = kc*4 + hl*2 + nt
// frag(j,t): o = w*32 + nt*16 + l16;  kglob = s*64 + kc*32 + quad*8 + e
__global__ void repack_embed(const void* __restrict__ W, f16* __restrict__ B,
                             const int* __restrict__ flagp) {
    const int is_f32 = *flagp;
    int idx = blockIdx.x * blockDim.x + threadIdx.x;
    if (idx >= 16 * 8 * 256 * 8) return;          // 262144 f16
    int e = idx & 7;
    int t = (idx >> 3) & 255;
    int j = (idx >> 11) & 7;
    int s = (idx >> 14) & 15;
    int w = t >> 6, lane = t & 63, quad = lane >> 4, l16 = lane & 15;
    int kc = j >> 2, hl = (j >> 1) & 1, nt = j & 1;
    int o  = w * 32 + nt * 16 + l16;
    int kg = s * 64 + kc * 32 + quad * 8 + e;
    int i = kg >> 4, trig = (kg >> 3) & 1, h = kg & 7;
    int widx = ((trig * C_HID + o) * C_IN + i) * C_H + h;
    f16 hi, lo; split16(load_in(W, widx, is_f32), hi, lo);
    B[idx] = hl ? lo : hi;
}

__global__ void repack_mp(const void* __restrict__ W, f16* __restrict__ B,
                          const int* __restrict__ flagp) {
    const int is_f32 = *flagp;
    int idx = blockIdx.x * blockDim.x + threadIdx.x;
    if (idx >= C_L * 32 * 8 * 256 * 8) return;    // 1572864 f16
    int e = idx & 7;
    int t = (idx >> 3) & 255;
    int j = (idx >> 11) & 7;
    int s = (idx >> 14) & 31;
    int l = idx >> 19;
    int w = t >> 6, lane = t & 63, quad = lane >> 4, l16 = lane & 15;
    int kc = j >> 2, hl = (j >> 1) & 1, nt = j & 1;
    int o  = w * 32 + nt * 16 + l16;
    int kg = s * 64 + kc * 32 + quad * 8 + e;
    int i = kg >> 4, trig = (kg >> 3) & 1, h = kg & 7;
    int widx = (((l * 2 + trig) * C_HID + o) * C_HID + i) * C_H + h;
    f16 hi, lo; split16(load_in(W, widx, is_f32), hi, lo);
    B[idx] = hl ? lo : hi;
}

// readout weights stay fp32 (tiny GEMM)
__global__ void repack_read(const void* __restrict__ W, float* __restrict__ B, const int* __restrict__ flagp) {
    const int is_f32 = *flagp;
    int idx = blockIdx.x * blockDim.x + threadIdx.x;
    if (idx >= 2 * C_LAT * C_HID * C_H) return;
    int h = idx & 7; int t = idx >> 3;
    int i = t & 127; t >>= 7;
    int o = t & 31; int trig = t >> 5;
    B[(i * 16 + trig * 8 + h) * C_LAT + o] = load_in(W, idx, is_f32);
}

// ---------- graph prep (v4 path: bucketed counting-sort was 5x worse — atomic
// serialization on ~25 cache lines + unchanged write amplification) ----------
__global__ void deg_count(const int* __restrict__ col, int* __restrict__ deg, int E, int N) {
    int idx = blockIdx.x * blockDim.x + threadIdx.x;
    if (idx >= E + N) return;
    int c = (idx < E) ? col[idx] : (idx - E);
    atomicAdd(&deg[c], 1);
}

__global__ void dinv_kernel(const int* __restrict__ deg, float* __restrict__ dinv, int N) {
    int n = blockIdx.x * blockDim.x + threadIdx.x;
    if (n >= N) return;
    dinv[n] = rsqrtf((float)deg[n]);   // deg >= 1 (self loop)
}

__global__ void graph_bounds(const int* __restrict__ batch, int* __restrict__ gstart, int N) {
    int g = threadIdx.x;
    if (g > C_G) return;
    int lo = 0, hi = N;
    while (lo < hi) {
        int mid = (lo + hi) >> 1;
        if (batch[mid] < g) lo = mid + 1; else hi = mid;
    }
    gstart[g] = lo;
}

// ---------- hierarchical exclusive scan of deg -> rowptr ----------
__global__ void scan1(const int* __restrict__ deg, int* __restrict__ rowptr,
                      int* __restrict__ bsum, int N) {
    __shared__ int sdata[1024];
    int i = blockIdx.x * 1024 + threadIdx.x;
    int v = (i < N) ? deg[i] : 0;
    sdata[threadIdx.x] = v;
    __syncthreads();
    for (int off = 1; off < 1024; off <<= 1) {
        int t = (threadIdx.x >= (unsigned)off) ? sdata[threadIdx.x - off] : 0;
        __syncthreads();
        sdata[threadIdx.x] += t;
        __syncthreads();
    }
    if (i < N) rowptr[i + 1] = sdata[threadIdx.x];
    if (threadIdx.x == 1023) bsum[blockIdx.x] = sdata[1023];
}

__global__ void scan2(int* __restrict__ bsum, int nb) {
    if (threadIdx.x == 0) {
        int acc = 0;
        for (int i = 0; i < nb; ++i) { int t = bsum[i]; bsum[i] = acc; acc += t; }
    }
}

__global__ void scan3(int* __restrict__ rowptr, const int* __restrict__ bsum, int N) {
    int i = blockIdx.x * 1024 + threadIdx.x;
    if (i < N) rowptr[i + 1] += bsum[blockIdx.x];
    if (i == 0) rowptr[0] = 0;
}

__global__ void csr_fill(const int* __restrict__ row, const int* __restrict__ col,
                         const int* __restrict__ rowptr, int* __restrict__ cursor,
                         int* __restrict__ srcs, int E, int N) {
    int idx = blockIdx.x * blockDim.x + threadIdx.x;
    if (idx >= E + N) return;
    int r, c;
    if (idx < E) { r = row[idx]; c = col[idx]; } else { r = c = idx - E; }
    int pos = rowptr[c] + atomicAdd(&cursor[c], 1);
    srcs[pos] = r;
}

// ---------- Phi split-fp16 generation into XOR-swizzled [64][64] A-tile ----------
// Row stride 64 f16 (128 B, no pad). 16-B chunk c of row r lives at chunk (c ^ (r&7)).
__device__ inline void phi_write_split(f16* __restrict__ Ah, f16* __restrict__ Al,
                                       int offC, int offS, float x) {
    float c[8], s[8];
    __sincosf(x, &s[0], &c[0]);
#pragma unroll
    for (int h = 1; h < 8; ++h) {
        c[h] = c[h-1] * c[0] - s[h-1] * s[0];
        s[h] = s[h-1] * c[0] + c[h-1] * s[0];
    }
    f16x8 ch, cl, sh, sl;
#pragma unroll
    for (int h = 0; h < 8; ++h) {
        f16 hi, lo;
        split16(c[h], hi, lo); ch[h] = hi; cl[h] = lo;
        split16(s[h], hi, lo); sh[h] = hi; sl[h] = lo;
    }
    *(f16x8*)&Ah[offC] = ch;
    *(f16x8*)&Ah[offS] = sh;
    *(f16x8*)&Al[offC] = cl;
    *(f16x8*)&Al[offS] = sl;
}

// ---------- split-fp16 MFMA fused-Phi GEMM: Y[M,128] = Phi(X)[M, INF*16] x Bt^T ----------
// K=64 stages, 1 barrier/stage, A ping-pong in swizzled LDS, B double-buffered in
// REGISTERS from fragment-major global layout (coalesced 16B/lane, L2-resident).
#define STAGE_BODY(S, BC, BN, ACUR_H, ACUR_L, ANXT_H, ANXT_L)                         \
  {                                                                                    \
    const int s_ = (S);                                                                \
    if (s_ + 1 < NST) {                                                                \
      _Pragma("unroll")                                                                \
      for (int j = 0; j < 8; ++j)                                                      \
        BN[j] = Bf[((size_t)(s_ + 1) * 8 + j) * 256 + tid];                            \
    }                                                                                  \
    float xf_ = 0.f;                                                                   \
    if (s_ + 2 < NST && rowok)                                                         \
      xf_ = load_in(X, (size_t)gm * INF + (s_ + 2) * 4 + pf, is_f32);                  \
    if (s_ + 1 < NST)                                                                  \
      phi_write_split(ANXT_H, ANXT_L, offC, offS, xn);                                 \
    _Pragma("unroll")                                                                  \
    for (int kc = 0; kc < 2; ++kc) {                                                   \
      f16x8 ah[4], al[4];                                                              \
      _Pragma("unroll")                                                                \
      for (int mt = 0; mt < 4; ++mt) {                                                 \
        int ro = (mt * 16 + l16) * 64 + (((kc * 4 + quad) ^ (l16 & 7)) * 8);           \
        ah[mt] = *(const f16x8*)&ACUR_H[ro];                                           \
        al[mt] = *(const f16x8*)&ACUR_L[ro];                                           \
      }                                                                                \
      __builtin_amdgcn_s_setprio(1);                                                   \
      _Pragma("unroll")                                                                \
      for (int mt = 0; mt < 4; ++mt)                                                   \
        _Pragma("unroll")                                                              \
        for (int nt = 0; nt < 2; ++nt) {                                               \
          acc[mt][nt] = __builtin_amdgcn_mfma_f32_16x16x32_f16(ah[mt], BC[kc*4+nt],   acc[mt][nt], 0, 0, 0); \
          acc[mt][nt] = __builtin_amdgcn_mfma_f32_16x16x32_f16(ah[mt], BC[kc*4+2+nt], acc[mt][nt], 0, 0, 0); \
          acc[mt][nt] = __builtin_amdgcn_mfma_f32_16x16x32_f16(al[mt], BC[kc*4+nt],   acc[mt][nt], 0, 0, 0); \
        }                                                                              \
      __builtin_amdgcn_s_setprio(0);                                                   \
    }                                                                                  \
    __syncthreads();                                                                   \
    xn = xf_;                                                                          \
  }

template<int INF, bool F16OUT>
__global__ __launch_bounds__(256, 3) void kan_gemm_mfma(const void* __restrict__ X,
                                                        const f16* __restrict__ Bt,
                                                        float* __restrict__ Yf, f16* __restrict__ Yh,
                                                        const float* __restrict__ dinv,
                                                        int M, const int* __restrict__ flagp) {
    constexpr int NST = INF / 4;     // stages of K=64 (4 input features each)
    __shared__ f16 AhB[2][64 * 64];
    __shared__ f16 AlB[2][64 * 64];
    __shared__ float dinvs[64];
    const int is_f32 = flagp ? *flagp : 1;
    const int tid  = threadIdx.x;
    const int m0   = blockIdx.x * 64;
    const int w    = tid >> 6, lane = tid & 63;
    const int quad = lane >> 4, l16 = lane & 15;

    // phi role: thread owns (row = lane, feature = w) each stage
    const int pf   = w;
    const int gm   = m0 + lane;
    const bool rowok = gm < M;
    const int offC = lane * 64 + (((w * 2)     ^ (lane & 7)) * 8);
    const int offS = lane * 64 + (((w * 2 + 1) ^ (lane & 7)) * 8);

    if (F16OUT && tid < 64) dinvs[tid] = (m0 + tid < M) ? dinv[m0 + tid] : 0.f;

    f32x4 acc[4][2] = {};
    const f16x8* __restrict__ Bf = (const f16x8*)Bt;

    f16x8 b0[8], b1[8];
#pragma unroll
    for (int j = 0; j < 8; ++j) b0[j] = Bf[(size_t)j * 256 + tid];

    float x0 = rowok ? load_in(X, (size_t)gm * INF + pf, is_f32) : 0.f;
    float xn = (NST > 1 && rowok) ? load_in(X, (size_t)gm * INF + 4 + pf, is_f32) : 0.f;

    phi_write_split(AhB[0], AlB[0], offC, offS, x0);
    __syncthreads();

    for (int s = 0; s < NST; s += 2) {
        STAGE_BODY(s,     b0, b1, AhB[0], AlB[0], AhB[1], AlB[1]);
        STAGE_BODY(s + 1, b1, b0, AhB[1], AlB[1], AhB[0], AlB[0]);
    }

    // C/D layout: col = lane&15, row = quad*4 + reg
#pragma unroll
    for (int mt = 0; mt < 4; ++mt) {
        int rloc = mt * 16 + quad * 4;
#pragma unroll
        for (int nt = 0; nt < 2; ++nt) {
            int cn = w * 32 + nt * 16 + l16;
#pragma unroll
            for (int r = 0; r < 4; ++r) {
                int m = m0 + rloc + r;
                if (m < M) {
                    if (F16OUT) Yh[(size_t)m * 128 + cn] = (f16)(acc[mt][nt][r] * dinvs[rloc + r]);
                    else        Yf[(size_t)m * 128 + cn] = acc[mt][nt][r];
                }
            }
        }
    }
}

// ---------- CSR aggregation: one wave per dest, 8-deep gather ILP ----------
__global__ __launch_bounds__(256) void aggregate(const f16* __restrict__ Hin, float* __restrict__ Hout,
                                                 const int* __restrict__ rowptr, const int* __restrict__ srcs,
                                                 const float* __restrict__ dinv, int N) {
    int wave = (int)((blockIdx.x * blockDim.x + threadIdx.x) >> 6);
    int lane = threadIdx.x & 63;
    if (wave >= N) return;
    const f16x2* H2 = (const f16x2*)Hin;
    int beg = rowptr[wave], end = rowptr[wave + 1];
    float2 a0 = {0.f, 0.f}, a1 = {0.f, 0.f}, a2 = {0.f, 0.f}, a3 = {0.f, 0.f};
    int j = beg;
    while (j < end) {
        int cnt = end - j; if (cnt > 64) cnt = 64;
        int sv = (lane < cnt) ? srcs[j + lane] : 0;
        int t = 0;
        for (; t + 8 <= cnt; t += 8) {
            int s0 = __shfl(sv, t + 0);
            int s1 = __shfl(sv, t + 1);
            int s2 = __shfl(sv, t + 2);
            int s3 = __shfl(sv, t + 3);
            int s4 = __shfl(sv, t + 4);
            int s5 = __shfl(sv, t + 5);
            int s6 = __shfl(sv, t + 6);
            int s7 = __shfl(sv, t + 7);
            f16x2 h0 = H2[(size_t)s0 * 64 + lane];
            f16x2 h1 = H2[(size_t)s1 * 64 + lane];
            f16x2 h2 = H2[(size_t)s2 * 64 + lane];
            f16x2 h3 = H2[(size_t)s3 * 64 + lane];
            f16x2 h4 = H2[(size_t)s4 * 64 + lane];
            f16x2 h5 = H2[(size_t)s5 * 64 + lane];
            f16x2 h6 = H2[(size_t)s6 * 64 + lane];
            f16x2 h7 = H2[(size_t)s7 * 64 + lane];
            a0.x += (float)h0[0] + (float)h1[0];
            a0.y += (float)h0[1] + (float)h1[1];
            a1.x += (float)h2[0] + (float)h3[0];
            a1.y += (float)h2[1] + (float)h3[1];
            a2.x += (float)h4[0] + (float)h5[0];
            a2.y += (float)h4[1] + (float)h5[1];
            a3.x += (float)h6[0] + (float)h7[0];
            a3.y += (float)h6[1] + (float)h7[1];
        }
        for (; t < cnt; ++t) {
            int s0 = __shfl(sv, t);
            f16x2 h0 = H2[(size_t)s0 * 64 + lane];
            a0.x += (float)h0[0];
            a0.y += (float)h0[1];
        }
        j += cnt;
    }
    float dv = dinv[wave];
    float2 acc = {(a0.x + a1.x + a2.x + a3.x) * dv, (a0.y + a1.y + a2.y + a3.y) * dv};
    ((float2*)Hout)[(size_t)wave * 64 + lane] = acc;
}

// ---------- mean-pool split: G*8 partial-sum blocks, then tiny readout ----------
// v6: old fused pool_readout ran G=64 blocks on 256 CUs (Occupancy 2.5%, 110 us,
// 126 GB/s). pool_partial spreads the 25.6 MB row-sum over 512 blocks (deterministic
// per-split partials, no atomics); pool_readout then reduces 8 partials per graph.
__global__ __launch_bounds__(256) void pool_partial(const float* __restrict__ H,
                                                    const int* __restrict__ gstart,
                                                    float* __restrict__ part) {
    int g = blockIdx.x >> 3, s = blockIdx.x & 7;
    int tid = threadIdx.x;
    int f = tid & 127, half = tid >> 7;
    int s0 = gstart[g], e0 = gstart[g + 1];
    int len = e0 - s0;
    int chunk = (len + 7) >> 3;
    int rs = s0 + s * chunk;
    int re = rs + chunk; if (re > e0) re = e0;
    float sum = 0.f;
    for (int n = rs + half; n < re; n += 2)
        sum += H[(size_t)n * C_HID + f];
    part[(size_t)blockIdx.x * 256 + tid] = sum;
}

__global__ __launch_bounds__(256) void pool_readout(const float* __restrict__ part, const int* __restrict__ gstart,
                                                    const float* __restrict__ B, void* __restrict__ out,
                                                    const int* __restrict__ flagp) {
    __shared__ float phi[2048];
    __shared__ float red[256];
    __shared__ float partl[8][32];
    const int is_f32 = *flagp;
    int g = blockIdx.x;
    int tid = threadIdx.x;
    float sum = 0.f;
#pragma unroll
    for (int s = 0; s < 8; ++s)
        sum += part[((size_t)g * 8 + s) * 256 + tid];
    red[tid] = sum;
    __syncthreads();
    if (tid < 128) {
        int s0 = gstart[g], e0 = gstart[g + 1];
        float cnt = fmaxf((float)(e0 - s0), 1.0f);
        float x = (red[tid] + red[tid + 128]) / cnt;
        float s1, c1;
        __sincosf(x, &s1, &c1);
        phi[tid * 16 + 0] = c1; phi[tid * 16 + 8] = s1;
        float ck = c1, sk = s1;
#pragma unroll
        for (int h = 1; h < 8; ++h) {
            float cn = ck * c1 - sk * s1;
            float sn = sk * c1 + ck * s1;
            phi[tid * 16 + h] = cn; phi[tid * 16 + 8 + h] = sn;
            ck = cn; sk = sn;
        }
    }
    __syncthreads();
    int o = tid & 31, p = tid >> 5;
    float acc = 0.f;
    for (int k = p * 256; k < p * 256 + 256; ++k)
        acc = fmaf(phi[k], B[k * C_LAT + o], acc);
    partl[p][o] = acc;
    __syncthreads();
    if (tid < 32) {
        float s = 0.f;
#pragma unroll
        for (int pp = 0; pp < 8; ++pp) s += partl[pp][tid];
        if (is_f32) ((float*)out)[g * C_LAT + tid] = s;
        else        ((bf16*)out)[g * C_LAT + tid] = __float2bfloat16(s);
    }
}

extern "C" void kernel_launch(void* const* d_in, const int* in_sizes, int n_in,
                              void* d_out, int out_size, void* d_ws, size_t ws_size,
                              hipStream_t stream) {
    const void* features = d_in[0];
    const int*  edge     = (const int*)d_in[1];
    const int*  batch    = (const int*)d_in[2];
    const void* W_embed  = d_in[3];
    const void* W_mp     = d_in[4];
    const void* W_read   = d_in[5];

    const int N = in_sizes[0] / C_IN;
    const int E = in_sizes[1] / 2;
    const int* row = edge;
    const int* col = edge + E;
    const int nScanBlocks = (N + 1023) / 1024;

    char* ws = (char*)d_ws;
    auto alloc = [&](size_t bytes) { char* p = ws; ws += (bytes + 255) & ~(size_t)255; return p; };
    float* h_a    = (float*)alloc((size_t)N * C_HID * 4);
    f16*   h16    = (f16*)alloc((size_t)N * C_HID * 2);
    f16*   Bte    = (f16*)alloc((size_t)16 * 8 * 256 * 8 * 2);          // 512 KB
    f16*   Btmp   = (f16*)alloc((size_t)C_L * 32 * 8 * 256 * 8 * 2);    // 3 MB
    float* Brd    = (float*)alloc((size_t)2048 * C_LAT * 4);
    float* ppart  = (float*)alloc((size_t)C_G * 8 * 256 * 4);           // 512 KB
    int*   deg    = (int*)alloc((size_t)N * 4);
    float* dinv   = (float*)alloc((size_t)N * 4);
    int*   rowptr = (int*)alloc((size_t)(N + 1) * 4);
    int*   cursor = (int*)alloc((size_t)N * 4);
    int*   srcs   = (int*)alloc((size_t)(E + N) * 4);
    int*   bsum   = (int*)alloc((size_t)nScanBlocks * 4);
    int*   gstart = (int*)alloc((size_t)(C_G + 1) * 4);
    int*   dflag  = (int*)alloc(256);

    hipMemsetAsync(deg, 0, (size_t)N * 4, stream);
    hipMemsetAsync(cursor, 0, (size_t)N * 4, stream);

    detect_dtype<<<1, 256, 0, stream>>>((const unsigned short*)W_embed, dflag);

    repack_embed<<<(16 * 8 * 256 * 8 + 255) / 256, 256, 0, stream>>>(W_embed, Bte, dflag);
    repack_mp<<<(C_L * 32 * 8 * 256 * 8 + 255) / 256, 256, 0, stream>>>(W_mp, Btmp, dflag);
    repack_read<<<(2 * C_LAT * C_HID * C_H + 255) / 256, 256, 0, stream>>>(W_read, Brd, dflag);

    deg_count<<<(E + N + 255) / 256, 256, 0, stream>>>(col, deg, E, N);
    dinv_kernel<<<(N + 255) / 256, 256, 0, stream>>>(deg, dinv, N);
    graph_bounds<<<1, 128, 0, stream>>>(batch, gstart, N);
    scan1<<<nScanBlocks, 1024, 0, stream>>>(deg, rowptr, bsum, N);
    scan2<<<1, 64, 0, stream>>>(bsum, nScanBlocks);
    scan3<<<nScanBlocks, 1024, 0, stream>>>(rowptr, bsum, N);
    csr_fill<<<(E + N + 255) / 256, 256, 0, stream>>>(row, col, rowptr, cursor, srcs, E, N);

    const int gemm_grid = (N + 63) / 64;
    kan_gemm_mfma<C_IN, false><<<gemm_grid, 256, 0, stream>>>(features, Bte, h_a, nullptr, nullptr, N, dflag);
    for (int l = 0; l < C_L; ++l) {
        kan_gemm_mfma<C_HID, true><<<gemm_grid, 256, 0, stream>>>(h_a, Btmp + (size_t)l * 32 * 8 * 256 * 8,
                                                                  nullptr, h16, dinv, N, nullptr);
        aggregate<<<((size_t)N * 64 + 255) / 256, 256, 0, stream>>>(h16, h_a, rowptr, srcs, dinv, N);
    }

    pool_partial<<<C_G * 8, 256, 0, stream>>>(h_a, gstart, ppart);
    pool_readout<<<C_G, 256, 0, stream>>>(ppart, gstart, Brd, d_out, dflag);
}

// Round 7
// 774.149 us; speedup vs baseline: 1.8588x; 1.0446x over previous
//
#include <hip/hip_runtime.h>
#include <hip/hip_bf16.h>
#include <cstdint>

typedef __hip_bfloat16 bf16;
typedef _Float16 f16;
typedef f16 f16x2 __attribute__((ext_vector_type(2)));
typedef f16 f16x8 __attribute__((ext_vector_type(8)));
typedef float f32x4 __attribute__((ext_vector_type(4)));

#define C_IN   64
#define C_HID  128
#define C_LAT  32
#define C_H    8
#define C_L    3
#define C_G    64

// Runtime input-dtype handling (harness may hand fp32 or bf16). flag==1 -> fp32.
__device__ inline float load_in(const void* p, size_t idx, int is_f32) {
    if (is_f32) return ((const float*)p)[idx];
    return __bfloat162float(((const bf16*)p)[idx]);
}

__global__ void detect_dtype(const unsigned short* __restrict__ W, int* __restrict__ flag) {
    __shared__ int cnt;
    if (threadIdx.x == 0) cnt = 0;
    __syncthreads();
    int local = 0;
    for (int i = threadIdx.x; i < 8192; i += 256) {
        int e = (W[i] >> 7) & 0xFF;
        if (e >= 135) local++;
    }
    atomicAdd(&cnt, local);
    __syncthreads();
    if (threadIdx.x == 0) *flag = (cnt > 64) ? 1 : 0;
}

__device__ inline void split16(float v, f16& hi, f16& lo) {
    hi = (f16)v;
    lo = (f16)(v - (float)hi);
}

// ---------- weight repack -> fragment-major split-f16 layout ----------
// B[((s*8 + j)*256 + t)*8 + e], j = kc*4 + hl*2 + nt
// frag(j,t): o = w*32 + nt*16 + l16;  kglob = s*64 + kc*32 + quad*8 + e
__global__ void repack_embed(const void* __restrict__ W, f16* __restrict__ B,
                             const int* __restrict__ flagp) {
    const int is_f32 = *flagp;
    int idx = blockIdx.x * blockDim.x + threadIdx.x;
    if (idx >= 16 * 8 * 256 * 8) return;          // 262144 f16
    int e = idx & 7;
    int t = (idx >> 3) & 255;
    int j = (idx >> 11) & 7;
    int s = (idx >> 14) & 15;
    int w = t >> 6, lane = t & 63, quad = lane >> 4, l16 = lane & 15;
    int kc = j >> 2, hl = (j >> 1) & 1, nt = j & 1;
    int o  = w * 32 + nt * 16 + l16;
    int kg = s * 64 + kc * 32 + quad * 8 + e;
    int i = kg >> 4, trig = (kg >> 3) & 1, h = kg & 7;
    int widx = ((trig * C_HID + o) * C_IN + i) * C_H + h;
    f16 hi, lo; split16(load_in(W, widx, is_f32), hi, lo);
    B[idx] = hl ? lo : hi;
}

__global__ void repack_mp(const void* __restrict__ W, f16* __restrict__ B,
                          const int* __restrict__ flagp) {
    const int is_f32 = *flagp;
    int idx = blockIdx.x * blockDim.x + threadIdx.x;
    if (idx >= C_L * 32 * 8 * 256 * 8) return;    // 1572864 f16
    int e = idx & 7;
    int t = (idx >> 3) & 255;
    int j = (idx >> 11) & 7;
    int s = (idx >> 14) & 31;
    int l = idx >> 19;
    int w = t >> 6, lane = t & 63, quad = lane >> 4, l16 = lane & 15;
    int kc = j >> 2, hl = (j >> 1) & 1, nt = j & 1;
    int o  = w * 32 + nt * 16 + l16;
    int kg = s * 64 + kc * 32 + quad * 8 + e;
    int i = kg >> 4, trig = (kg >> 3) & 1, h = kg & 7;
    int widx = (((l * 2 + trig) * C_HID + o) * C_HID + i) * C_H + h;
    f16 hi, lo; split16(load_in(W, widx, is_f32), hi, lo);
    B[idx] = hl ? lo : hi;
}

// readout weights stay fp32 (tiny GEMM)
__global__ void repack_read(const void* __restrict__ W, float* __restrict__ B, const int* __restrict__ flagp) {
    const int is_f32 = *flagp;
    int idx = blockIdx.x * blockDim.x + threadIdx.x;
    if (idx >= 2 * C_LAT * C_HID * C_H) return;
    int h = idx & 7; int t = idx >> 3;
    int i = t & 127; t >>= 7;
    int o = t & 31; int trig = t >> 5;
    B[(i * 16 + trig * 8 + h) * C_LAT + o] = load_in(W, idx, is_f32);
}

// ---------- graph prep ----------
__global__ void deg_count(const int* __restrict__ col, int* __restrict__ deg, int E, int N) {
    int idx = blockIdx.x * blockDim.x + threadIdx.x;
    if (idx >= E + N) return;
    int c = (idx < E) ? col[idx] : (idx - E);
    atomicAdd(&deg[c], 1);
}

__global__ void dinv_kernel(const int* __restrict__ deg, float* __restrict__ dinv, int N) {
    int n = blockIdx.x * blockDim.x + threadIdx.x;
    if (n >= N) return;
    dinv[n] = rsqrtf((float)deg[n]);   // deg >= 1 (self loop)
}

__global__ void graph_bounds(const int* __restrict__ batch, int* __restrict__ gstart, int N) {
    int g = threadIdx.x;
    if (g > C_G) return;
    int lo = 0, hi = N;
    while (lo < hi) {
        int mid = (lo + hi) >> 1;
        if (batch[mid] < g) lo = mid + 1; else hi = mid;
    }
    gstart[g] = lo;
}

// ---------- hierarchical exclusive scan of deg -> rowptr ----------
__global__ void scan1(const int* __restrict__ deg, int* __restrict__ rowptr,
                      int* __restrict__ bsum, int N) {
    __shared__ int sdata[1024];
    int i = blockIdx.x * 1024 + threadIdx.x;
    int v = (i < N) ? deg[i] : 0;
    sdata[threadIdx.x] = v;
    __syncthreads();
    for (int off = 1; off < 1024; off <<= 1) {
        int t = (threadIdx.x >= (unsigned)off) ? sdata[threadIdx.x - off] : 0;
        __syncthreads();
        sdata[threadIdx.x] += t;
        __syncthreads();
    }
    if (i < N) rowptr[i + 1] = sdata[threadIdx.x];
    if (threadIdx.x == 1023) bsum[blockIdx.x] = sdata[1023];
}

__global__ void scan2(int* __restrict__ bsum, int nb) {
    if (threadIdx.x == 0) {
        int acc = 0;
        for (int i = 0; i < nb; ++i) { int t = bsum[i]; bsum[i] = acc; acc += t; }
    }
}

__global__ void scan3(int* __restrict__ rowptr, const int* __restrict__ bsum, int N) {
    int i = blockIdx.x * 1024 + threadIdx.x;
    if (i < N) rowptr[i + 1] += bsum[blockIdx.x];
    if (i == 0) rowptr[0] = 0;
}

// ---------- CSR fill ----------
// v7 theory: old csr_fill's 103 MB WRITE = one full-line writeback PER STORE — a node's
// window is written ~33 times from random CUs on all 8 XCDs; lines evict between writes
// and sectors ping-pong across non-coherent L2s. Fix: block (chunk=b>>3, group=b&7)
// commits only dests in node-range 'group'. Every (chunk,group) pair runs exactly once
// -> correct for ANY block->XCD mapping. With round-robin XCD dispatch, each srcs
// eighth (u16: 412 KB, L2-resident) is written by one XCD only -> writes coalesce,
// cursor atomics stay XCD-local. Cost: 8x edge-list re-read (L3-resident).
__global__ __launch_bounds__(256) void csr_fill_part(const int* __restrict__ row, const int* __restrict__ col,
                                                     const int* __restrict__ rowptr, int* __restrict__ cursor,
                                                     unsigned short* __restrict__ srcs, int E, int N,
                                                     int nchunks) {
    int grp = blockIdx.x & 7;
    int chunk = blockIdx.x >> 3;
    int rsz = (N + 7) >> 3;
    int lo = grp * rsz;
    int hi = lo + rsz; if (hi > N) hi = N;
    int total = E + N;
    int per = (total + nchunks - 1) / nchunks;
    int start = chunk * per;
    int stop = start + per; if (stop > total) stop = total;
    for (int idx = start + threadIdx.x; idx < stop; idx += 256) {
        int r, c;
        if (idx < E) { r = row[idx]; c = col[idx]; } else { r = c = idx - E; }
        if (c >= lo && c < hi) {
            int pos = rowptr[c] + atomicAdd(&cursor[c], 1);
            srcs[pos] = (unsigned short)r;
        }
    }
}

// fallback (N > 65536): original int-scatter path
__global__ void csr_fill(const int* __restrict__ row, const int* __restrict__ col,
                         const int* __restrict__ rowptr, int* __restrict__ cursor,
                         int* __restrict__ srcs, int E, int N) {
    int idx = blockIdx.x * blockDim.x + threadIdx.x;
    if (idx >= E + N) return;
    int r, c;
    if (idx < E) { r = row[idx]; c = col[idx]; } else { r = c = idx - E; }
    int pos = rowptr[c] + atomicAdd(&cursor[c], 1);
    srcs[pos] = r;
}

// ---------- Phi split-fp16 generation into XOR-swizzled [64][64] A-tile ----------
// Row stride 64 f16 (128 B, no pad). 16-B chunk c of row r lives at chunk (c ^ (r&7)).
__device__ inline void phi_write_split(f16* __restrict__ Ah, f16* __restrict__ Al,
                                       int offC, int offS, float x) {
    float c[8], s[8];
    __sincosf(x, &s[0], &c[0]);
#pragma unroll
    for (int h = 1; h < 8; ++h) {
        c[h] = c[h-1] * c[0] - s[h-1] * s[0];
        s[h] = s[h-1] * c[0] + c[h-1] * s[0];
    }
    f16x8 ch, cl, sh, sl;
#pragma unroll
    for (int h = 0; h < 8; ++h) {
        f16 hi, lo;
        split16(c[h], hi, lo); ch[h] = hi; cl[h] = lo;
        split16(s[h], hi, lo); sh[h] = hi; sl[h] = lo;
    }
    *(f16x8*)&Ah[offC] = ch;
    *(f16x8*)&Ah[offS] = sh;
    *(f16x8*)&Al[offC] = cl;
    *(f16x8*)&Al[offS] = sl;
}

// ---------- split-fp16 MFMA fused-Phi GEMM: Y[M,128] = Phi(X)[M, INF*16] x Bt^T ----------
// K=64 stages, 1 barrier/stage, A ping-pong in swizzled LDS, B double-buffered in
// REGISTERS from fragment-major global layout (coalesced 16B/lane, L2-resident).
#define STAGE_BODY(S, BC, BN, ACUR_H, ACUR_L, ANXT_H, ANXT_L)                         \
  {                                                                                    \
    const int s_ = (S);                                                                \
    if (s_ + 1 < NST) {                                                                \
      _Pragma("unroll")                                                                \
      for (int j = 0; j < 8; ++j)                                                      \
        BN[j] = Bf[((size_t)(s_ + 1) * 8 + j) * 256 + tid];                            \
    }                                                                                  \
    float xf_ = 0.f;                                                                   \
    if (s_ + 2 < NST && rowok)                                                         \
      xf_ = load_in(X, (size_t)gm * INF + (s_ + 2) * 4 + pf, is_f32);                  \
    if (s_ + 1 < NST)                                                                  \
      phi_write_split(ANXT_H, ANXT_L, offC, offS, xn);                                 \
    _Pragma("unroll")                                                                  \
    for (int kc = 0; kc < 2; ++kc) {                                                   \
      f16x8 ah[4], al[4];                                                              \
      _Pragma("unroll")                                                                \
      for (int mt = 0; mt < 4; ++mt) {                                                 \
        int ro = (mt * 16 + l16) * 64 + (((kc * 4 + quad) ^ (l16 & 7)) * 8);           \
        ah[mt] = *(const f16x8*)&ACUR_H[ro];                                           \
        al[mt] = *(const f16x8*)&ACUR_L[ro];                                           \
      }                                                                                \
      __builtin_amdgcn_s_setprio(1);                                                   \
      _Pragma("unroll")                                                                \
      for (int mt = 0; mt < 4; ++mt)                                                   \
        _Pragma("unroll")                                                              \
        for (int nt = 0; nt < 2; ++nt) {                                               \
          acc[mt][nt] = __builtin_amdgcn_mfma_f32_16x16x32_f16(ah[mt], BC[kc*4+nt],   acc[mt][nt], 0, 0, 0); \
          acc[mt][nt] = __builtin_amdgcn_mfma_f32_16x16x32_f16(ah[mt], BC[kc*4+2+nt], acc[mt][nt], 0, 0, 0); \
          acc[mt][nt] = __builtin_amdgcn_mfma_f32_16x16x32_f16(al[mt], BC[kc*4+nt],   acc[mt][nt], 0, 0, 0); \
        }                                                                              \
      __builtin_amdgcn_s_setprio(0);                                                   \
    }                                                                                  \
    __syncthreads();                                                                   \
    xn = xf_;                                                                          \
  }

template<int INF, bool F16OUT>
__global__ __launch_bounds__(256, 3) void kan_gemm_mfma(const void* __restrict__ X,
                                                        const f16* __restrict__ Bt,
                                                        float* __restrict__ Yf, f16* __restrict__ Yh,
                                                        const float* __restrict__ dinv,
                                                        int M, const int* __restrict__ flagp) {
    constexpr int NST = INF / 4;     // stages of K=64 (4 input features each)
    __shared__ f16 AhB[2][64 * 64];
    __shared__ f16 AlB[2][64 * 64];
    __shared__ float dinvs[64];
    const int is_f32 = flagp ? *flagp : 1;
    const int tid  = threadIdx.x;
    const int m0   = blockIdx.x * 64;
    const int w    = tid >> 6, lane = tid & 63;
    const int quad = lane >> 4, l16 = lane & 15;

    // phi role: thread owns (row = lane, feature = w) each stage
    const int pf   = w;
    const int gm   = m0 + lane;
    const bool rowok = gm < M;
    const int offC = lane * 64 + (((w * 2)     ^ (lane & 7)) * 8);
    const int offS = lane * 64 + (((w * 2 + 1) ^ (lane & 7)) * 8);

    if (F16OUT && tid < 64) dinvs[tid] = (m0 + tid < M) ? dinv[m0 + tid] : 0.f;

    f32x4 acc[4][2] = {};
    const f16x8* __restrict__ Bf = (const f16x8*)Bt;

    f16x8 b0[8], b1[8];
#pragma unroll
    for (int j = 0; j < 8; ++j) b0[j] = Bf[(size_t)j * 256 + tid];

    float x0 = rowok ? load_in(X, (size_t)gm * INF + pf, is_f32) : 0.f;
    float xn = (NST > 1 && rowok) ? load_in(X, (size_t)gm * INF + 4 + pf, is_f32) : 0.f;

    phi_write_split(AhB[0], AlB[0], offC, offS, x0);
    __syncthreads();

    for (int s = 0; s < NST; s += 2) {
        STAGE_BODY(s,     b0, b1, AhB[0], AlB[0], AhB[1], AlB[1]);
        STAGE_BODY(s + 1, b1, b0, AhB[1], AlB[1], AhB[0], AlB[0]);
    }

    // C/D layout: col = lane&15, row = quad*4 + reg
#pragma unroll
    for (int mt = 0; mt < 4; ++mt) {
        int rloc = mt * 16 + quad * 4;
#pragma unroll
        for (int nt = 0; nt < 2; ++nt) {
            int cn = w * 32 + nt * 16 + l16;
#pragma unroll
            for (int r = 0; r < 4; ++r) {
                int m = m0 + rloc + r;
                if (m < M) {
                    if (F16OUT) Yh[(size_t)m * 128 + cn] = (f16)(acc[mt][nt][r] * dinvs[rloc + r]);
                    else        Yf[(size_t)m * 128 + cn] = acc[mt][nt][r];
                }
            }
        }
    }
}

// ---------- CSR aggregation: one wave per dest, 8-deep gather ILP ----------
template<typename IT>
__global__ __launch_bounds__(256) void aggregate(const f16* __restrict__ Hin, float* __restrict__ Hout,
                                                 const int* __restrict__ rowptr, const IT* __restrict__ srcs,
                                                 const float* __restrict__ dinv, int N) {
    int wave = (int)((blockIdx.x * blockDim.x + threadIdx.x) >> 6);
    int lane = threadIdx.x & 63;
    if (wave >= N) return;
    const f16x2* H2 = (const f16x2*)Hin;
    int beg = rowptr[wave], end = rowptr[wave + 1];
    float2 a0 = {0.f, 0.f}, a1 = {0.f, 0.f}, a2 = {0.f, 0.f}, a3 = {0.f, 0.f};
    int j = beg;
    while (j < end) {
        int cnt = end - j; if (cnt > 64) cnt = 64;
        int sv = (lane < cnt) ? (int)srcs[j + lane] : 0;
        int t = 0;
        for (; t + 8 <= cnt; t += 8) {
            int s0 = __shfl(sv, t + 0);
            int s1 = __shfl(sv, t + 1);
            int s2 = __shfl(sv, t + 2);
            int s3 = __shfl(sv, t + 3);
            int s4 = __shfl(sv, t + 4);
            int s5 = __shfl(sv, t + 5);
            int s6 = __shfl(sv, t + 6);
            int s7 = __shfl(sv, t + 7);
            f16x2 h0 = H2[(size_t)s0 * 64 + lane];
            f16x2 h1 = H2[(size_t)s1 * 64 + lane];
            f16x2 h2 = H2[(size_t)s2 * 64 + lane];
            f16x2 h3 = H2[(size_t)s3 * 64 + lane];
            f16x2 h4 = H2[(size_t)s4 * 64 + lane];
            f16x2 h5 = H2[(size_t)s5 * 64 + lane];
            f16x2 h6 = H2[(size_t)s6 * 64 + lane];
            f16x2 h7 = H2[(size_t)s7 * 64 + lane];
            a0.x += (float)h0[0] + (float)h1[0];
            a0.y += (float)h0[1] + (float)h1[1];
            a1.x += (float)h2[0] + (float)h3[0];
            a1.y += (float)h2[1] + (float)h3[1];
            a2.x += (float)h4[0] + (float)h5[0];
            a2.y += (float)h4[1] + (float)h5[1];
            a3.x += (float)h6[0] + (float)h7[0];
            a3.y += (float)h6[1] + (float)h7[1];
        }
        for (; t < cnt; ++t) {
            int s0 = __shfl(sv, t);
            f16x2 h0 = H2[(size_t)s0 * 64 + lane];
            a0.x += (float)h0[0];
            a0.y += (float)h0[1];
        }
        j += cnt;
    }
    float dv = dinv[wave];
    float2 acc = {(a0.x + a1.x + a2.x + a3.x) * dv, (a0.y + a1.y + a2.y + a3.y) * dv};
    ((float2*)Hout)[(size_t)wave * 64 + lane] = acc;
}

// ---------- mean-pool split: G*8 partial-sum blocks, then tiny readout ----------
__global__ __launch_bounds__(256) void pool_partial(const float* __restrict__ H,
                                                    const int* __restrict__ gstart,
                                                    float* __restrict__ part) {
    int g = blockIdx.x >> 3, s = blockIdx.x & 7;
    int tid = threadIdx.x;
    int f = tid & 127, half = tid >> 7;
    int s0 = gstart[g], e0 = gstart[g + 1];
    int len = e0 - s0;
    int chunk = (len + 7) >> 3;
    int rs = s0 + s * chunk;
    int re = rs + chunk; if (re > e0) re = e0;
    float sum = 0.f;
    for (int n = rs + half; n < re; n += 2)
        sum += H[(size_t)n * C_HID + f];
    part[(size_t)blockIdx.x * 256 + tid] = sum;
}

__global__ __launch_bounds__(256) void pool_readout(const float* __restrict__ part, const int* __restrict__ gstart,
                                                    const float* __restrict__ B, void* __restrict__ out,
                                                    const int* __restrict__ flagp) {
    __shared__ float phi[2048];
    __shared__ float red[256];
    __shared__ float partl[8][32];
    const int is_f32 = *flagp;
    int g = blockIdx.x;
    int tid = threadIdx.x;
    float sum = 0.f;
#pragma unroll
    for (int s = 0; s < 8; ++s)
        sum += part[((size_t)g * 8 + s) * 256 + tid];
    red[tid] = sum;
    __syncthreads();
    if (tid < 128) {
        int s0 = gstart[g], e0 = gstart[g + 1];
        float cnt = fmaxf((float)(e0 - s0), 1.0f);
        float x = (red[tid] + red[tid + 128]) / cnt;
        float s1, c1;
        __sincosf(x, &s1, &c1);
        phi[tid * 16 + 0] = c1; phi[tid * 16 + 8] = s1;
        float ck = c1, sk = s1;
#pragma unroll
        for (int h = 1; h < 8; ++h) {
            float cn = ck * c1 - sk * s1;
            float sn = sk * c1 + ck * s1;
            phi[tid * 16 + h] = cn; phi[tid * 16 + 8 + h] = sn;
            ck = cn; sk = sn;
        }
    }
    __syncthreads();
    int o = tid & 31, p = tid >> 5;
    float acc = 0.f;
    for (int k = p * 256; k < p * 256 + 256; ++k)
        acc = fmaf(phi[k], B[k * C_LAT + o], acc);
    partl[p][o] = acc;
    __syncthreads();
    if (tid < 32) {
        float s = 0.f;
#pragma unroll
        for (int pp = 0; pp < 8; ++pp) s += partl[pp][tid];
        if (is_f32) ((float*)out)[g * C_LAT + tid] = s;
        else        ((bf16*)out)[g * C_LAT + tid] = __float2bfloat16(s);
    }
}

extern "C" void kernel_launch(void* const* d_in, const int* in_sizes, int n_in,
                              void* d_out, int out_size, void* d_ws, size_t ws_size,
                              hipStream_t stream) {
    const void* features = d_in[0];
    const int*  edge     = (const int*)d_in[1];
    const int*  batch    = (const int*)d_in[2];
    const void* W_embed  = d_in[3];
    const void* W_mp     = d_in[4];
    const void* W_read   = d_in[5];

    const int N = in_sizes[0] / C_IN;
    const int E = in_sizes[1] / 2;
    const int* row = edge;
    const int* col = edge + E;
    const int nScanBlocks = (N + 1023) / 1024;
    const bool packed_ok = (N <= 65536);

    char* ws = (char*)d_ws;
    auto alloc = [&](size_t bytes) { char* p = ws; ws += (bytes + 255) & ~(size_t)255; return p; };
    float* h_a    = (float*)alloc((size_t)N * C_HID * 4);
    f16*   h16    = (f16*)alloc((size_t)N * C_HID * 2);
    f16*   Bte    = (f16*)alloc((size_t)16 * 8 * 256 * 8 * 2);          // 512 KB
    f16*   Btmp   = (f16*)alloc((size_t)C_L * 32 * 8 * 256 * 8 * 2);    // 3 MB
    float* Brd    = (float*)alloc((size_t)2048 * C_LAT * 4);
    float* ppart  = (float*)alloc((size_t)C_G * 8 * 256 * 4);           // 512 KB
    int*   deg    = (int*)alloc((size_t)N * 4);
    float* dinv   = (float*)alloc((size_t)N * 4);
    int*   rowptr = (int*)alloc((size_t)(N + 1) * 4);
    int*   cursor = (int*)alloc((size_t)N * 4);
    unsigned short* srcs16 = (unsigned short*)alloc((size_t)(E + N) * 2);
    int*   srcs32 = (int*)alloc(packed_ok ? 256 : (size_t)(E + N) * 4);
    int*   bsum   = (int*)alloc((size_t)nScanBlocks * 4);
    int*   gstart = (int*)alloc((size_t)(C_G + 1) * 4);
    int*   dflag  = (int*)alloc(256);

    hipMemsetAsync(deg, 0, (size_t)N * 4, stream);
    hipMemsetAsync(cursor, 0, (size_t)N * 4, stream);

    detect_dtype<<<1, 256, 0, stream>>>((const unsigned short*)W_embed, dflag);

    repack_embed<<<(16 * 8 * 256 * 8 + 255) / 256, 256, 0, stream>>>(W_embed, Bte, dflag);
    repack_mp<<<(C_L * 32 * 8 * 256 * 8 + 255) / 256, 256, 0, stream>>>(W_mp, Btmp, dflag);
    repack_read<<<(2 * C_LAT * C_HID * C_H + 255) / 256, 256, 0, stream>>>(W_read, Brd, dflag);

    deg_count<<<(E + N + 255) / 256, 256, 0, stream>>>(col, deg, E, N);
    dinv_kernel<<<(N + 255) / 256, 256, 0, stream>>>(deg, dinv, N);
    graph_bounds<<<1, 128, 0, stream>>>(batch, gstart, N);
    scan1<<<nScanBlocks, 1024, 0, stream>>>(deg, rowptr, bsum, N);
    scan2<<<1, 64, 0, stream>>>(bsum, nScanBlocks);
    scan3<<<nScanBlocks, 1024, 0, stream>>>(rowptr, bsum, N);
    if (packed_ok) {
        const int nchunks = 256;
        csr_fill_part<<<nchunks * 8, 256, 0, stream>>>(row, col, rowptr, cursor, srcs16, E, N, nchunks);
    } else {
        csr_fill<<<(E + N + 255) / 256, 256, 0, stream>>>(row, col, rowptr, cursor, srcs32, E, N);
    }

    const int gemm_grid = (N + 63) / 64;
    kan_gemm_mfma<C_IN, false><<<gemm_grid, 256, 0, stream>>>(features, Bte, h_a, nullptr, nullptr, N, dflag);
    for (int l = 0; l < C_L; ++l) {
        kan_gemm_mfma<C_HID, true><<<gemm_grid, 256, 0, stream>>>(h_a, Btmp + (size_t)l * 32 * 8 * 256 * 8,
                                                                  nullptr, h16, dinv, N, nullptr);
        if (packed_ok)
            aggregate<unsigned short><<<((size_t)N * 64 + 255) / 256, 256, 0, stream>>>(h16, h_a, rowptr, srcs16, dinv, N);
        else
            aggregate<int><<<((size_t)N * 64 + 255) / 256, 256, 0, stream>>>(h16, h_a, rowptr, srcs32, dinv, N);
    }

    pool_partial<<<C_G * 8, 256, 0, stream>>>(h_a, gstart, ppart);
    pool_readout<<<C_G, 256, 0, stream>>>(ppart, gstart, Brd, d_out, dflag);
}

// Round 8
// 684.262 us; speedup vs baseline: 2.1030x; 1.1314x over previous
//
#include <hip/hip_runtime.h>
#include <hip/hip_bf16.h>
#include <cstdint>

typedef __hip_bfloat16 bf16;
typedef _Float16 f16;
typedef f16 f16x2 __attribute__((ext_vector_type(2)));
typedef f16 f16x8 __attribute__((ext_vector_type(8)));
typedef float f32x4 __attribute__((ext_vector_type(4)));

#define C_IN   64
#define C_HID  128
#define C_LAT  32
#define C_H    8
#define C_L    3
#define C_G    64

// Runtime input-dtype handling (harness may hand fp32 or bf16). flag==1 -> fp32.
__device__ inline float load_in(const void* p, size_t idx, int is_f32) {
    if (is_f32) return ((const float*)p)[idx];
    return __bfloat162float(((const bf16*)p)[idx]);
}

__global__ void detect_dtype(const unsigned short* __restrict__ W, int* __restrict__ flag) {
    __shared__ int cnt;
    if (threadIdx.x == 0) cnt = 0;
    __syncthreads();
    int local = 0;
    for (int i = threadIdx.x; i < 8192; i += 256) {
        int e = (W[i] >> 7) & 0xFF;
        if (e >= 135) local++;
    }
    atomicAdd(&cnt, local);
    __syncthreads();
    if (threadIdx.x == 0) *flag = (cnt > 64) ? 1 : 0;
}

__device__ inline void split16(float v, f16& hi, f16& lo) {
    hi = (f16)v;
    lo = (f16)(v - (float)hi);
}

// ---------- weight repack -> fragment-major split-f16 layout ----------
// B[((s*8 + j)*256 + t)*8 + e], j = kc*4 + hl*2 + nt
// frag(j,t): o = w*32 + nt*16 + l16;  kglob = s*64 + kc*32 + quad*8 + e
// B keeps the hi/lo split (weights are repacked once; phi is now plain f16 — v8).
__global__ void repack_embed(const void* __restrict__ W, f16* __restrict__ B,
                             const int* __restrict__ flagp) {
    const int is_f32 = *flagp;
    int idx = blockIdx.x * blockDim.x + threadIdx.x;
    if (idx >= 16 * 8 * 256 * 8) return;          // 262144 f16
    int e = idx & 7;
    int t = (idx >> 3) & 255;
    int j = (idx >> 11) & 7;
    int s = (idx >> 14) & 15;
    int w = t >> 6, lane = t & 63, quad = lane >> 4, l16 = lane & 15;
    int kc = j >> 2, hl = (j >> 1) & 1, nt = j & 1;
    int o  = w * 32 + nt * 16 + l16;
    int kg = s * 64 + kc * 32 + quad * 8 + e;
    int i = kg >> 4, trig = (kg >> 3) & 1, h = kg & 7;
    int widx = ((trig * C_HID + o) * C_IN + i) * C_H + h;
    f16 hi, lo; split16(load_in(W, widx, is_f32), hi, lo);
    B[idx] = hl ? lo : hi;
}

__global__ void repack_mp(const void* __restrict__ W, f16* __restrict__ B,
                          const int* __restrict__ flagp) {
    const int is_f32 = *flagp;
    int idx = blockIdx.x * blockDim.x + threadIdx.x;
    if (idx >= C_L * 32 * 8 * 256 * 8) return;    // 1572864 f16
    int e = idx & 7;
    int t = (idx >> 3) & 255;
    int j = (idx >> 11) & 7;
    int s = (idx >> 14) & 31;
    int l = idx >> 19;
    int w = t >> 6, lane = t & 63, quad = lane >> 4, l16 = lane & 15;
    int kc = j >> 2, hl = (j >> 1) & 1, nt = j & 1;
    int o  = w * 32 + nt * 16 + l16;
    int kg = s * 64 + kc * 32 + quad * 8 + e;
    int i = kg >> 4, trig = (kg >> 3) & 1, h = kg & 7;
    int widx = (((l * 2 + trig) * C_HID + o) * C_HID + i) * C_H + h;
    f16 hi, lo; split16(load_in(W, widx, is_f32), hi, lo);
    B[idx] = hl ? lo : hi;
}

// readout weights stay fp32 (tiny GEMM)
__global__ void repack_read(const void* __restrict__ W, float* __restrict__ B, const int* __restrict__ flagp) {
    const int is_f32 = *flagp;
    int idx = blockIdx.x * blockDim.x + threadIdx.x;
    if (idx >= 2 * C_LAT * C_HID * C_H) return;
    int h = idx & 7; int t = idx >> 3;
    int i = t & 127; t >>= 7;
    int o = t & 31; int trig = t >> 5;
    B[(i * 16 + trig * 8 + h) * C_LAT + o] = load_in(W, idx, is_f32);
}

// ---------- graph prep ----------
__global__ void deg_count(const int* __restrict__ col, int* __restrict__ deg, int E, int N) {
    int idx = blockIdx.x * blockDim.x + threadIdx.x;
    if (idx >= E + N) return;
    int c = (idx < E) ? col[idx] : (idx - E);
    atomicAdd(&deg[c], 1);
}

__global__ void dinv_kernel(const int* __restrict__ deg, float* __restrict__ dinv, int N) {
    int n = blockIdx.x * blockDim.x + threadIdx.x;
    if (n >= N) return;
    dinv[n] = rsqrtf((float)deg[n]);   // deg >= 1 (self loop)
}

__global__ void graph_bounds(const int* __restrict__ batch, int* __restrict__ gstart, int N) {
    int g = threadIdx.x;
    if (g > C_G) return;
    int lo = 0, hi = N;
    while (lo < hi) {
        int mid = (lo + hi) >> 1;
        if (batch[mid] < g) lo = mid + 1; else hi = mid;
    }
    gstart[g] = lo;
}

// ---------- hierarchical exclusive scan of deg -> rowptr ----------
__global__ void scan1(const int* __restrict__ deg, int* __restrict__ rowptr,
                      int* __restrict__ bsum, int N) {
    __shared__ int sdata[1024];
    int i = blockIdx.x * 1024 + threadIdx.x;
    int v = (i < N) ? deg[i] : 0;
    sdata[threadIdx.x] = v;
    __syncthreads();
    for (int off = 1; off < 1024; off <<= 1) {
        int t = (threadIdx.x >= (unsigned)off) ? sdata[threadIdx.x - off] : 0;
        __syncthreads();
        sdata[threadIdx.x] += t;
        __syncthreads();
    }
    if (i < N) rowptr[i + 1] = sdata[threadIdx.x];
    if (threadIdx.x == 1023) bsum[blockIdx.x] = sdata[1023];
}

__global__ void scan2(int* __restrict__ bsum, int nb) {
    if (threadIdx.x == 0) {
        int acc = 0;
        for (int i = 0; i < nb; ++i) { int t = bsum[i]; bsum[i] = acc; acc += t; }
    }
}

__global__ void scan3(int* __restrict__ rowptr, const int* __restrict__ bsum, int N) {
    int i = blockIdx.x * 1024 + threadIdx.x;
    if (i < N) rowptr[i + 1] += bsum[blockIdx.x];
    if (i == 0) rowptr[0] = 0;
}

// ---------- CSR fill: XCD-confined filtered multi-sweep (v7, verified -34 us) ----------
__global__ __launch_bounds__(256) void csr_fill_part(const int* __restrict__ row, const int* __restrict__ col,
                                                     const int* __restrict__ rowptr, int* __restrict__ cursor,
                                                     unsigned short* __restrict__ srcs, int E, int N,
                                                     int nchunks) {
    int grp = blockIdx.x & 7;
    int chunk = blockIdx.x >> 3;
    int rsz = (N + 7) >> 3;
    int lo = grp * rsz;
    int hi = lo + rsz; if (hi > N) hi = N;
    int total = E + N;
    int per = (total + nchunks - 1) / nchunks;
    int start = chunk * per;
    int stop = start + per; if (stop > total) stop = total;
    for (int idx = start + threadIdx.x; idx < stop; idx += 256) {
        int r, c;
        if (idx < E) { r = row[idx]; c = col[idx]; } else { r = c = idx - E; }
        if (c >= lo && c < hi) {
            int pos = rowptr[c] + atomicAdd(&cursor[c], 1);
            srcs[pos] = (unsigned short)r;
        }
    }
}

// fallback (N > 65536): original int-scatter path
__global__ void csr_fill(const int* __restrict__ row, const int* __restrict__ col,
                         const int* __restrict__ rowptr, int* __restrict__ cursor,
                         int* __restrict__ srcs, int E, int N) {
    int idx = blockIdx.x * blockDim.x + threadIdx.x;
    if (idx >= E + N) return;
    int r, c;
    if (idx < E) { r = row[idx]; c = col[idx]; } else { r = c = idx - E; }
    int pos = rowptr[c] + atomicAdd(&cursor[c], 1);
    srcs[pos] = r;
}

// ---------- Phi (plain f16) into XOR-swizzled [64][64] A-tile ----------
// v8: drop the phi lo-split. Error from the omitted Al*B term is ~3e-4 per output —
// same order as the EXISTING f16 h16 inter-layer quantization, which demonstrably
// keeps final absmax at one bf16 ulp. Chebyshev recurrence: 2 ops/harmonic.
__device__ inline void phi_write(f16* __restrict__ Ah, int offC, int offS, float x) {
    float c[8], s[8];
    __sincosf(x, &s[0], &c[0]);
    float t2 = 2.f * c[0];
    c[1] = t2 * c[0] - 1.f;        // cos2x = 2c^2 - 1
    s[1] = t2 * s[0];              // sin2x = 2sc
#pragma unroll
    for (int h = 2; h < 8; ++h) {
        c[h] = t2 * c[h-1] - c[h-2];
        s[h] = t2 * s[h-1] - s[h-2];
    }
    f16x8 ch, sh;
#pragma unroll
    for (int h = 0; h < 8; ++h) { ch[h] = (f16)c[h]; sh[h] = (f16)s[h]; }
    *(f16x8*)&Ah[offC] = ch;
    *(f16x8*)&Ah[offS] = sh;
}

// ---------- 2-MFMA fused-Phi GEMM: Y[M,128] = Phi(X)[M, INF*16] x (Bh+Bl)^T ----------
// K=64 stages, 1 barrier/stage, phi-f16 ping-pong in swizzled LDS (16 KB total),
// B (hi/lo split) double-buffered in registers from fragment-major global layout.
// Per (mt,nt,kc): acc = mfma(ah,bh) then mfma(ah,bl)  -> 16 MFMA/stage (was 24).
#define STAGE_BODY(S, BC, BN, ACUR, ANXT)                                             \
  {                                                                                    \
    const int s_ = (S);                                                                \
    if (s_ + 1 < NST) {                                                                \
      _Pragma("unroll")                                                                \
      for (int j = 0; j < 8; ++j)                                                      \
        BN[j] = Bf[((size_t)(s_ + 1) * 8 + j) * 256 + tid];                            \
    }                                                                                  \
    float xf_ = 0.f;                                                                   \
    if (s_ + 2 < NST && rowok)                                                         \
      xf_ = load_in(X, (size_t)gm * INF + (s_ + 2) * 4 + pf, is_f32);                  \
    if (s_ + 1 < NST)                                                                  \
      phi_write(ANXT, offC, offS, xn);                                                 \
    _Pragma("unroll")                                                                  \
    for (int kc = 0; kc < 2; ++kc) {                                                   \
      f16x8 ah[4];                                                                     \
      _Pragma("unroll")                                                                \
      for (int mt = 0; mt < 4; ++mt) {                                                 \
        int ro = (mt * 16 + l16) * 64 + (((kc * 4 + quad) ^ (l16 & 7)) * 8);           \
        ah[mt] = *(const f16x8*)&ACUR[ro];                                             \
      }                                                                                \
      __builtin_amdgcn_s_setprio(1);                                                   \
      _Pragma("unroll")                                                                \
      for (int mt = 0; mt < 4; ++mt)                                                   \
        _Pragma("unroll")                                                              \
        for (int nt = 0; nt < 2; ++nt) {                                               \
          acc[mt][nt] = __builtin_amdgcn_mfma_f32_16x16x32_f16(ah[mt], BC[kc*4+nt],   acc[mt][nt], 0, 0, 0); \
          acc[mt][nt] = __builtin_amdgcn_mfma_f32_16x16x32_f16(ah[mt], BC[kc*4+2+nt], acc[mt][nt], 0, 0, 0); \
        }                                                                              \
      __builtin_amdgcn_s_setprio(0);                                                   \
    }                                                                                  \
    __syncthreads();                                                                   \
    xn = xf_;                                                                          \
  }

template<int INF, bool F16OUT>
__global__ __launch_bounds__(256, 4) void kan_gemm_mfma(const void* __restrict__ X,
                                                        const f16* __restrict__ Bt,
                                                        float* __restrict__ Yf, f16* __restrict__ Yh,
                                                        const float* __restrict__ dinv,
                                                        int M, const int* __restrict__ flagp) {
    constexpr int NST = INF / 4;     // stages of K=64 (4 input features each)
    __shared__ f16 AhB[2][64 * 64];
    __shared__ float dinvs[64];
    const int is_f32 = flagp ? *flagp : 1;
    const int tid  = threadIdx.x;
    const int m0   = blockIdx.x * 64;
    const int w    = tid >> 6, lane = tid & 63;
    const int quad = lane >> 4, l16 = lane & 15;

    // phi role: thread owns (row = lane, feature = w) each stage
    const int pf   = w;
    const int gm   = m0 + lane;
    const bool rowok = gm < M;
    const int offC = lane * 64 + (((w * 2)     ^ (lane & 7)) * 8);
    const int offS = lane * 64 + (((w * 2 + 1) ^ (lane & 7)) * 8);

    if (F16OUT && tid < 64) dinvs[tid] = (m0 + tid < M) ? dinv[m0 + tid] : 0.f;

    f32x4 acc[4][2] = {};
    const f16x8* __restrict__ Bf = (const f16x8*)Bt;

    f16x8 b0[8], b1[8];
#pragma unroll
    for (int j = 0; j < 8; ++j) b0[j] = Bf[(size_t)j * 256 + tid];

    float x0 = rowok ? load_in(X, (size_t)gm * INF + pf, is_f32) : 0.f;
    float xn = (NST > 1 && rowok) ? load_in(X, (size_t)gm * INF + 4 + pf, is_f32) : 0.f;

    phi_write(AhB[0], offC, offS, x0);
    __syncthreads();

    for (int s = 0; s < NST; s += 2) {
        STAGE_BODY(s,     b0, b1, AhB[0], AhB[1]);
        STAGE_BODY(s + 1, b1, b0, AhB[1], AhB[0]);
    }

    // C/D layout: col = lane&15, row = quad*4 + reg
#pragma unroll
    for (int mt = 0; mt < 4; ++mt) {
        int rloc = mt * 16 + quad * 4;
#pragma unroll
        for (int nt = 0; nt < 2; ++nt) {
            int cn = w * 32 + nt * 16 + l16;
#pragma unroll
            for (int r = 0; r < 4; ++r) {
                int m = m0 + rloc + r;
                if (m < M) {
                    if (F16OUT) Yh[(size_t)m * 128 + cn] = (f16)(acc[mt][nt][r] * dinvs[rloc + r]);
                    else        Yf[(size_t)m * 128 + cn] = acc[mt][nt][r];
                }
            }
        }
    }
}

// ---------- CSR aggregation: one wave per dest, 8-deep gather ILP ----------
template<typename IT>
__global__ __launch_bounds__(256) void aggregate(const f16* __restrict__ Hin, float* __restrict__ Hout,
                                                 const int* __restrict__ rowptr, const IT* __restrict__ srcs,
                                                 const float* __restrict__ dinv, int N) {
    int wave = (int)((blockIdx.x * blockDim.x + threadIdx.x) >> 6);
    int lane = threadIdx.x & 63;
    if (wave >= N) return;
    const f16x2* H2 = (const f16x2*)Hin;
    int beg = rowptr[wave], end = rowptr[wave + 1];
    float2 a0 = {0.f, 0.f}, a1 = {0.f, 0.f}, a2 = {0.f, 0.f}, a3 = {0.f, 0.f};
    int j = beg;
    while (j < end) {
        int cnt = end - j; if (cnt > 64) cnt = 64;
        int sv = (lane < cnt) ? (int)srcs[j + lane] : 0;
        int t = 0;
        for (; t + 8 <= cnt; t += 8) {
            int s0 = __shfl(sv, t + 0);
            int s1 = __shfl(sv, t + 1);
            int s2 = __shfl(sv, t + 2);
            int s3 = __shfl(sv, t + 3);
            int s4 = __shfl(sv, t + 4);
            int s5 = __shfl(sv, t + 5);
            int s6 = __shfl(sv, t + 6);
            int s7 = __shfl(sv, t + 7);
            f16x2 h0 = H2[(size_t)s0 * 64 + lane];
            f16x2 h1 = H2[(size_t)s1 * 64 + lane];
            f16x2 h2 = H2[(size_t)s2 * 64 + lane];
            f16x2 h3 = H2[(size_t)s3 * 64 + lane];
            f16x2 h4 = H2[(size_t)s4 * 64 + lane];
            f16x2 h5 = H2[(size_t)s5 * 64 + lane];
            f16x2 h6 = H2[(size_t)s6 * 64 + lane];
            f16x2 h7 = H2[(size_t)s7 * 64 + lane];
            a0.x += (float)h0[0] + (float)h1[0];
            a0.y += (float)h0[1] + (float)h1[1];
            a1.x += (float)h2[0] + (float)h3[0];
            a1.y += (float)h2[1] + (float)h3[1];
            a2.x += (float)h4[0] + (float)h5[0];
            a2.y += (float)h4[1] + (float)h5[1];
            a3.x += (float)h6[0] + (float)h7[0];
            a3.y += (float)h6[1] + (float)h7[1];
        }
        for (; t < cnt; ++t) {
            int s0 = __shfl(sv, t);
            f16x2 h0 = H2[(size_t)s0 * 64 + lane];
            a0.x += (float)h0[0];
            a0.y += (float)h0[1];
        }
        j += cnt;
    }
    float dv = dinv[wave];
    float2 acc = {(a0.x + a1.x + a2.x + a3.x) * dv, (a0.y + a1.y + a2.y + a3.y) * dv};
    ((float2*)Hout)[(size_t)wave * 64 + lane] = acc;
}

// ---------- mean-pool split: G*8 partial-sum blocks, then tiny readout ----------
__global__ __launch_bounds__(256) void pool_partial(const float* __restrict__ H,
                                                    const int* __restrict__ gstart,
                                                    float* __restrict__ part) {
    int g = blockIdx.x >> 3, s = blockIdx.x & 7;
    int tid = threadIdx.x;
    int f = tid & 127, half = tid >> 7;
    int s0 = gstart[g], e0 = gstart[g + 1];
    int len = e0 - s0;
    int chunk = (len + 7) >> 3;
    int rs = s0 + s * chunk;
    int re = rs + chunk; if (re > e0) re = e0;
    float sum = 0.f;
    for (int n = rs + half; n < re; n += 2)
        sum += H[(size_t)n * C_HID + f];
    part[(size_t)blockIdx.x * 256 + tid] = sum;
}

__global__ __launch_bounds__(256) void pool_readout(const float* __restrict__ part, const int* __restrict__ gstart,
                                                    const float* __restrict__ B, void* __restrict__ out,
                                                    const int* __restrict__ flagp) {
    __shared__ float phi[2048];
    __shared__ float red[256];
    __shared__ float partl[8][32];
    const int is_f32 = *flagp;
    int g = blockIdx.x;
    int tid = threadIdx.x;
    float sum = 0.f;
#pragma unroll
    for (int s = 0; s < 8; ++s)
        sum += part[((size_t)g * 8 + s) * 256 + tid];
    red[tid] = sum;
    __syncthreads();
    if (tid < 128) {
        int s0 = gstart[g], e0 = gstart[g + 1];
        float cnt = fmaxf((float)(e0 - s0), 1.0f);
        float x = (red[tid] + red[tid + 128]) / cnt;
        float s1, c1;
        __sincosf(x, &s1, &c1);
        phi[tid * 16 + 0] = c1; phi[tid * 16 + 8] = s1;
        float ck = c1, sk = s1;
#pragma unroll
        for (int h = 1; h < 8; ++h) {
            float cn = ck * c1 - sk * s1;
            float sn = sk * c1 + ck * s1;
            phi[tid * 16 + h] = cn; phi[tid * 16 + 8 + h] = sn;
            ck = cn; sk = sn;
        }
    }
    __syncthreads();
    int o = tid & 31, p = tid >> 5;
    float acc = 0.f;
    for (int k = p * 256; k < p * 256 + 256; ++k)
        acc = fmaf(phi[k], B[k * C_LAT + o], acc);
    partl[p][o] = acc;
    __syncthreads();
    if (tid < 32) {
        float s = 0.f;
#pragma unroll
        for (int pp = 0; pp < 8; ++pp) s += partl[pp][tid];
        if (is_f32) ((float*)out)[g * C_LAT + tid] = s;
        else        ((bf16*)out)[g * C_LAT + tid] = __float2bfloat16(s);
    }
}

extern "C" void kernel_launch(void* const* d_in, const int* in_sizes, int n_in,
                              void* d_out, int out_size, void* d_ws, size_t ws_size,
                              hipStream_t stream) {
    const void* features = d_in[0];
    const int*  edge     = (const int*)d_in[1];
    const int*  batch    = (const int*)d_in[2];
    const void* W_embed  = d_in[3];
    const void* W_mp     = d_in[4];
    const void* W_read   = d_in[5];

    const int N = in_sizes[0] / C_IN;
    const int E = in_sizes[1] / 2;
    const int* row = edge;
    const int* col = edge + E;
    const int nScanBlocks = (N + 1023) / 1024;
    const bool packed_ok = (N <= 65536);

    char* ws = (char*)d_ws;
    auto alloc = [&](size_t bytes) { char* p = ws; ws += (bytes + 255) & ~(size_t)255; return p; };
    float* h_a    = (float*)alloc((size_t)N * C_HID * 4);
    f16*   h16    = (f16*)alloc((size_t)N * C_HID * 2);
    f16*   Bte    = (f16*)alloc((size_t)16 * 8 * 256 * 8 * 2);          // 512 KB
    f16*   Btmp   = (f16*)alloc((size_t)C_L * 32 * 8 * 256 * 8 * 2);    // 3 MB
    float* Brd    = (float*)alloc((size_t)2048 * C_LAT * 4);
    float* ppart  = (float*)alloc((size_t)C_G * 8 * 256 * 4);           // 512 KB
    int*   deg    = (int*)alloc((size_t)N * 4);
    float* dinv   = (float*)alloc((size_t)N * 4);
    int*   rowptr = (int*)alloc((size_t)(N + 1) * 4);
    int*   cursor = (int*)alloc((size_t)N * 4);
    unsigned short* srcs16 = (unsigned short*)alloc((size_t)(E + N) * 2);
    int*   srcs32 = (int*)alloc(packed_ok ? 256 : (size_t)(E + N) * 4);
    int*   bsum   = (int*)alloc((size_t)nScanBlocks * 4);
    int*   gstart = (int*)alloc((size_t)(C_G + 1) * 4);
    int*   dflag  = (int*)alloc(256);

    hipMemsetAsync(deg, 0, (size_t)N * 4, stream);
    hipMemsetAsync(cursor, 0, (size_t)N * 4, stream);

    detect_dtype<<<1, 256, 0, stream>>>((const unsigned short*)W_embed, dflag);

    repack_embed<<<(16 * 8 * 256 * 8 + 255) / 256, 256, 0, stream>>>(W_embed, Bte, dflag);
    repack_mp<<<(C_L * 32 * 8 * 256 * 8 + 255) / 256, 256, 0, stream>>>(W_mp, Btmp, dflag);
    repack_read<<<(2 * C_LAT * C_HID * C_H + 255) / 256, 256, 0, stream>>>(W_read, Brd, dflag);

    deg_count<<<(E + N + 255) / 256, 256, 0, stream>>>(col, deg, E, N);
    dinv_kernel<<<(N + 255) / 256, 256, 0, stream>>>(deg, dinv, N);
    graph_bounds<<<1, 128, 0, stream>>>(batch, gstart, N);
    scan1<<<nScanBlocks, 1024, 0, stream>>>(deg, rowptr, bsum, N);
    scan2<<<1, 64, 0, stream>>>(bsum, nScanBlocks);
    scan3<<<nScanBlocks, 1024, 0, stream>>>(rowptr, bsum, N);
    if (packed_ok) {
        const int nchunks = 256;
        csr_fill_part<<<nchunks * 8, 256, 0, stream>>>(row, col, rowptr, cursor, srcs16, E, N, nchunks);
    } else {
        csr_fill<<<(E + N + 255) / 256, 256, 0, stream>>>(row, col, rowptr, cursor, srcs32, E, N);
    }

    const int gemm_grid = (N + 63) / 64;
    kan_gemm_mfma<C_IN, false><<<gemm_grid, 256, 0, stream>>>(features, Bte, h_a, nullptr, nullptr, N, dflag);
    for (int l = 0; l < C_L; ++l) {
        kan_gemm_mfma<C_HID, true><<<gemm_grid, 256, 0, stream>>>(h_a, Btmp + (size_t)l * 32 * 8 * 256 * 8,
                                                                  nullptr, h16, dinv, N, nullptr);
        if (packed_ok)
            aggregate<unsigned short><<<((size_t)N * 64 + 255) / 256, 256, 0, stream>>>(h16, h_a, rowptr, srcs16, dinv, N);
        else
            aggregate<int><<<((size_t)N * 64 + 255) / 256, 256, 0, stream>>>(h16, h_a, rowptr, srcs32, dinv, N);
    }

    pool_partial<<<C_G * 8, 256, 0, stream>>>(h_a, gstart, ppart);
    pool_readout<<<C_G, 256, 0, stream>>>(ppart, gstart, Brd, d_out, dflag);
}

// Round 9
// 573.646 us; speedup vs baseline: 2.5085x; 1.1928x over previous
//
#include <hip/hip_runtime.h>
#include <hip/hip_bf16.h>
#include <cstdint>

typedef __hip_bfloat16 bf16;
typedef _Float16 f16;
typedef f16 f16x2 __attribute__((ext_vector_type(2)));
typedef f16 f16x8 __attribute__((ext_vector_type(8)));
typedef float f32x4 __attribute__((ext_vector_type(4)));

#define C_IN   64
#define C_HID  128
#define C_LAT  32
#define C_H    8
#define C_L    3
#define C_G    64

// Runtime input-dtype handling (harness may hand fp32 or bf16). flag==1 -> fp32.
__device__ inline float load_in(const void* p, size_t idx, int is_f32) {
    if (is_f32) return ((const float*)p)[idx];
    return __bfloat162float(((const bf16*)p)[idx]);
}

__global__ void detect_dtype(const unsigned short* __restrict__ W, int* __restrict__ flag) {
    __shared__ int cnt;
    if (threadIdx.x == 0) cnt = 0;
    __syncthreads();
    int local = 0;
    for (int i = threadIdx.x; i < 8192; i += 256) {
        int e = (W[i] >> 7) & 0xFF;
        if (e >= 135) local++;
    }
    atomicAdd(&cnt, local);
    __syncthreads();
    if (threadIdx.x == 0) *flag = (cnt > 64) ? 1 : 0;
}

// ---------- weight repack -> fragment-major single-f16 layout ----------
// v9: dropped the B hi/lo split. Error budget: rel 5e-4 on ~0.03-magnitude weights,
// sqrt(K)=45 accumulation -> ~7e-4 added drift; total pre-quantization drift ~1.7e-3
// < bf16 half-ulp 0.0039, so output (bf16-quantized) stays within 1 ulp of reference
// (absmax pinned at 0.0078125 through identical-order injections in v8).
// B[((s*4 + j)*256 + t)*8 + e], j = kc*2 + nt
// frag(j,t): o = w*32 + nt*16 + l16;  kglob = s*64 + kc*32 + quad*8 + e
__global__ void repack_embed(const void* __restrict__ W, f16* __restrict__ B,
                             const int* __restrict__ flagp) {
    const int is_f32 = *flagp;
    int idx = blockIdx.x * blockDim.x + threadIdx.x;
    if (idx >= 16 * 4 * 256 * 8) return;          // 131072 f16
    int e = idx & 7;
    int t = (idx >> 3) & 255;
    int j = (idx >> 11) & 3;
    int s = idx >> 13;
    int w = t >> 6, lane = t & 63, quad = lane >> 4, l16 = lane & 15;
    int kc = j >> 1, nt = j & 1;
    int o  = w * 32 + nt * 16 + l16;
    int kg = s * 64 + kc * 32 + quad * 8 + e;
    int i = kg >> 4, trig = (kg >> 3) & 1, h = kg & 7;
    int widx = ((trig * C_HID + o) * C_IN + i) * C_H + h;
    B[idx] = (f16)load_in(W, widx, is_f32);
}

__global__ void repack_mp(const void* __restrict__ W, f16* __restrict__ B,
                          const int* __restrict__ flagp) {
    const int is_f32 = *flagp;
    int idx = blockIdx.x * blockDim.x + threadIdx.x;
    if (idx >= C_L * 32 * 4 * 256 * 8) return;    // 786432 f16
    int e = idx & 7;
    int t = (idx >> 3) & 255;
    int j = (idx >> 11) & 3;
    int s = (idx >> 13) & 31;
    int l = idx >> 18;
    int w = t >> 6, lane = t & 63, quad = lane >> 4, l16 = lane & 15;
    int kc = j >> 1, nt = j & 1;
    int o  = w * 32 + nt * 16 + l16;
    int kg = s * 64 + kc * 32 + quad * 8 + e;
    int i = kg >> 4, trig = (kg >> 3) & 1, h = kg & 7;
    int widx = (((l * 2 + trig) * C_HID + o) * C_HID + i) * C_H + h;
    B[idx] = (f16)load_in(W, widx, is_f32);
}

// readout weights stay fp32 (tiny GEMM)
__global__ void repack_read(const void* __restrict__ W, float* __restrict__ B, const int* __restrict__ flagp) {
    const int is_f32 = *flagp;
    int idx = blockIdx.x * blockDim.x + threadIdx.x;
    if (idx >= 2 * C_LAT * C_HID * C_H) return;
    int h = idx & 7; int t = idx >> 3;
    int i = t & 127; t >>= 7;
    int o = t & 31; int trig = t >> 5;
    B[(i * 16 + trig * 8 + h) * C_LAT + o] = load_in(W, idx, is_f32);
}

// ---------- graph prep ----------
__global__ void deg_count(const int* __restrict__ col, int* __restrict__ deg, int E, int N) {
    int idx = blockIdx.x * blockDim.x + threadIdx.x;
    if (idx >= E + N) return;
    int c = (idx < E) ? col[idx] : (idx - E);
    atomicAdd(&deg[c], 1);
}

__global__ void dinv_kernel(const int* __restrict__ deg, float* __restrict__ dinv, int N) {
    int n = blockIdx.x * blockDim.x + threadIdx.x;
    if (n >= N) return;
    dinv[n] = rsqrtf((float)deg[n]);   // deg >= 1 (self loop)
}

__global__ void graph_bounds(const int* __restrict__ batch, int* __restrict__ gstart, int N) {
    int g = threadIdx.x;
    if (g > C_G) return;
    int lo = 0, hi = N;
    while (lo < hi) {
        int mid = (lo + hi) >> 1;
        if (batch[mid] < g) lo = mid + 1; else hi = mid;
    }
    gstart[g] = lo;
}

// ---------- hierarchical exclusive scan of deg -> rowptr ----------
__global__ void scan1(const int* __restrict__ deg, int* __restrict__ rowptr,
                      int* __restrict__ bsum, int N) {
    __shared__ int sdata[1024];
    int i = blockIdx.x * 1024 + threadIdx.x;
    int v = (i < N) ? deg[i] : 0;
    sdata[threadIdx.x] = v;
    __syncthreads();
    for (int off = 1; off < 1024; off <<= 1) {
        int t = (threadIdx.x >= (unsigned)off) ? sdata[threadIdx.x - off] : 0;
        __syncthreads();
        sdata[threadIdx.x] += t;
        __syncthreads();
    }
    if (i < N) rowptr[i + 1] = sdata[threadIdx.x];
    if (threadIdx.x == 1023) bsum[blockIdx.x] = sdata[1023];
}

__global__ void scan2(int* __restrict__ bsum, int nb) {
    if (threadIdx.x == 0) {
        int acc = 0;
        for (int i = 0; i < nb; ++i) { int t = bsum[i]; bsum[i] = acc; acc += t; }
    }
}

__global__ void scan3(int* __restrict__ rowptr, const int* __restrict__ bsum, int N) {
    int i = blockIdx.x * 1024 + threadIdx.x;
    if (i < N) rowptr[i + 1] += bsum[blockIdx.x];
    if (i == 0) rowptr[0] = 0;
}

// ---------- CSR fill: XCD-confined filtered multi-sweep (v7, verified -34 us) ----------
__global__ __launch_bounds__(256) void csr_fill_part(const int* __restrict__ row, const int* __restrict__ col,
                                                     const int* __restrict__ rowptr, int* __restrict__ cursor,
                                                     unsigned short* __restrict__ srcs, int E, int N,
                                                     int nchunks) {
    int grp = blockIdx.x & 7;
    int chunk = blockIdx.x >> 3;
    int rsz = (N + 7) >> 3;
    int lo = grp * rsz;
    int hi = lo + rsz; if (hi > N) hi = N;
    int total = E + N;
    int per = (total + nchunks - 1) / nchunks;
    int start = chunk * per;
    int stop = start + per; if (stop > total) stop = total;
    for (int idx = start + threadIdx.x; idx < stop; idx += 256) {
        int r, c;
        if (idx < E) { r = row[idx]; c = col[idx]; } else { r = c = idx - E; }
        if (c >= lo && c < hi) {
            int pos = rowptr[c] + atomicAdd(&cursor[c], 1);
            srcs[pos] = (unsigned short)r;
        }
    }
}

// fallback (N > 65536): original int-scatter path
__global__ void csr_fill(const int* __restrict__ row, const int* __restrict__ col,
                         const int* __restrict__ rowptr, int* __restrict__ cursor,
                         int* __restrict__ srcs, int E, int N) {
    int idx = blockIdx.x * blockDim.x + threadIdx.x;
    if (idx >= E + N) return;
    int r, c;
    if (idx < E) { r = row[idx]; c = col[idx]; } else { r = c = idx - E; }
    int pos = rowptr[c] + atomicAdd(&cursor[c], 1);
    srcs[pos] = r;
}

// ---------- Phi (plain f16) into XOR-swizzled [64][64] A-tile ----------
// Chebyshev recurrence: 2 ops/harmonic. 16-B chunk c of row r lives at chunk (c ^ (r&7)).
__device__ inline void phi_write(f16* __restrict__ Ah, int offC, int offS, float x) {
    float c[8], s[8];
    __sincosf(x, &s[0], &c[0]);
    float t2 = 2.f * c[0];
    c[1] = t2 * c[0] - 1.f;        // cos2x = 2c^2 - 1
    s[1] = t2 * s[0];              // sin2x = 2sc
#pragma unroll
    for (int h = 2; h < 8; ++h) {
        c[h] = t2 * c[h-1] - c[h-2];
        s[h] = t2 * s[h-1] - s[h-2];
    }
    f16x8 ch, sh;
#pragma unroll
    for (int h = 0; h < 8; ++h) { ch[h] = (f16)c[h]; sh[h] = (f16)s[h]; }
    *(f16x8*)&Ah[offC] = ch;
    *(f16x8*)&Ah[offS] = sh;
}

// ---------- 1-MFMA-per-tile fused-Phi GEMM: Y[M,128] = Phi(X)[M, INF*16] x B^T ----------
// K=64 stages, 1 barrier/stage, phi-f16 ping-pong in swizzled LDS, single-f16 B
// double-buffered in registers (4 frags/stage) from fragment-major global layout.
// 8 MFMA/stage (was 16 with split-B).
#define STAGE_BODY(S, BC, BN, ACUR, ANXT)                                             \
  {                                                                                    \
    const int s_ = (S);                                                                \
    if (s_ + 1 < NST) {                                                                \
      _Pragma("unroll")                                                                \
      for (int j = 0; j < 4; ++j)                                                      \
        BN[j] = Bf[((size_t)(s_ + 1) * 4 + j) * 256 + tid];                            \
    }                                                                                  \
    float xf_ = 0.f;                                                                   \
    if (s_ + 2 < NST && rowok)                                                         \
      xf_ = load_in(X, (size_t)gm * INF + (s_ + 2) * 4 + pf, is_f32);                  \
    if (s_ + 1 < NST)                                                                  \
      phi_write(ANXT, offC, offS, xn);                                                 \
    _Pragma("unroll")                                                                  \
    for (int kc = 0; kc < 2; ++kc) {                                                   \
      f16x8 ah[4];                                                                     \
      _Pragma("unroll")                                                                \
      for (int mt = 0; mt < 4; ++mt) {                                                 \
        int ro = (mt * 16 + l16) * 64 + (((kc * 4 + quad) ^ (l16 & 7)) * 8);           \
        ah[mt] = *(const f16x8*)&ACUR[ro];                                             \
      }                                                                                \
      __builtin_amdgcn_s_setprio(1);                                                   \
      _Pragma("unroll")                                                                \
      for (int mt = 0; mt < 4; ++mt)                                                   \
        _Pragma("unroll")                                                              \
        for (int nt = 0; nt < 2; ++nt)                                                 \
          acc[mt][nt] = __builtin_amdgcn_mfma_f32_16x16x32_f16(ah[mt], BC[kc*2+nt], acc[mt][nt], 0, 0, 0); \
      __builtin_amdgcn_s_setprio(0);                                                   \
    }                                                                                  \
    __syncthreads();                                                                   \
    xn = xf_;                                                                          \
  }

template<int INF, bool F16OUT>
__global__ __launch_bounds__(256, 4) void kan_gemm_mfma(const void* __restrict__ X,
                                                        const f16* __restrict__ Bt,
                                                        float* __restrict__ Yf, f16* __restrict__ Yh,
                                                        const float* __restrict__ dinv,
                                                        int M, const int* __restrict__ flagp) {
    constexpr int NST = INF / 4;     // stages of K=64 (4 input features each)
    __shared__ f16 AhB[2][64 * 64];
    __shared__ float dinvs[64];
    const int is_f32 = flagp ? *flagp : 1;
    const int tid  = threadIdx.x;
    const int m0   = blockIdx.x * 64;
    const int w    = tid >> 6, lane = tid & 63;
    const int quad = lane >> 4, l16 = lane & 15;

    // phi role: thread owns (row = lane, feature = w) each stage
    const int pf   = w;
    const int gm   = m0 + lane;
    const bool rowok = gm < M;
    const int offC = lane * 64 + (((w * 2)     ^ (lane & 7)) * 8);
    const int offS = lane * 64 + (((w * 2 + 1) ^ (lane & 7)) * 8);

    if (F16OUT && tid < 64) dinvs[tid] = (m0 + tid < M) ? dinv[m0 + tid] : 0.f;

    f32x4 acc[4][2] = {};
    const f16x8* __restrict__ Bf = (const f16x8*)Bt;

    f16x8 b0[4], b1[4];
#pragma unroll
    for (int j = 0; j < 4; ++j) b0[j] = Bf[(size_t)j * 256 + tid];

    float x0 = rowok ? load_in(X, (size_t)gm * INF + pf, is_f32) : 0.f;
    float xn = (NST > 1 && rowok) ? load_in(X, (size_t)gm * INF + 4 + pf, is_f32) : 0.f;

    phi_write(AhB[0], offC, offS, x0);
    __syncthreads();

    for (int s = 0; s < NST; s += 2) {
        STAGE_BODY(s,     b0, b1, AhB[0], AhB[1]);
        STAGE_BODY(s + 1, b1, b0, AhB[1], AhB[0]);
    }

    // C/D layout: col = lane&15, row = quad*4 + reg
#pragma unroll
    for (int mt = 0; mt < 4; ++mt) {
        int rloc = mt * 16 + quad * 4;
#pragma unroll
        for (int nt = 0; nt < 2; ++nt) {
            int cn = w * 32 + nt * 16 + l16;
#pragma unroll
            for (int r = 0; r < 4; ++r) {
                int m = m0 + rloc + r;
                if (m < M) {
                    if (F16OUT) Yh[(size_t)m * 128 + cn] = (f16)(acc[mt][nt][r] * dinvs[rloc + r]);
                    else        Yf[(size_t)m * 128 + cn] = acc[mt][nt][r];
                }
            }
        }
    }
}

// ---------- CSR aggregation: one wave per dest, 8-deep gather ILP ----------
template<typename IT>
__global__ __launch_bounds__(256) void aggregate(const f16* __restrict__ Hin, float* __restrict__ Hout,
                                                 const int* __restrict__ rowptr, const IT* __restrict__ srcs,
                                                 const float* __restrict__ dinv, int N) {
    int wave = (int)((blockIdx.x * blockDim.x + threadIdx.x) >> 6);
    int lane = threadIdx.x & 63;
    if (wave >= N) return;
    const f16x2* H2 = (const f16x2*)Hin;
    int beg = rowptr[wave], end = rowptr[wave + 1];
    float2 a0 = {0.f, 0.f}, a1 = {0.f, 0.f}, a2 = {0.f, 0.f}, a3 = {0.f, 0.f};
    int j = beg;
    while (j < end) {
        int cnt = end - j; if (cnt > 64) cnt = 64;
        int sv = (lane < cnt) ? (int)srcs[j + lane] : 0;
        int t = 0;
        for (; t + 8 <= cnt; t += 8) {
            int s0 = __shfl(sv, t + 0);
            int s1 = __shfl(sv, t + 1);
            int s2 = __shfl(sv, t + 2);
            int s3 = __shfl(sv, t + 3);
            int s4 = __shfl(sv, t + 4);
            int s5 = __shfl(sv, t + 5);
            int s6 = __shfl(sv, t + 6);
            int s7 = __shfl(sv, t + 7);
            f16x2 h0 = H2[(size_t)s0 * 64 + lane];
            f16x2 h1 = H2[(size_t)s1 * 64 + lane];
            f16x2 h2 = H2[(size_t)s2 * 64 + lane];
            f16x2 h3 = H2[(size_t)s3 * 64 + lane];
            f16x2 h4 = H2[(size_t)s4 * 64 + lane];
            f16x2 h5 = H2[(size_t)s5 * 64 + lane];
            f16x2 h6 = H2[(size_t)s6 * 64 + lane];
            f16x2 h7 = H2[(size_t)s7 * 64 + lane];
            a0.x += (float)h0[0] + (float)h1[0];
            a0.y += (float)h0[1] + (float)h1[1];
            a1.x += (float)h2[0] + (float)h3[0];
            a1.y += (float)h2[1] + (float)h3[1];
            a2.x += (float)h4[0] + (float)h5[0];
            a2.y += (float)h4[1] + (float)h5[1];
            a3.x += (float)h6[0] + (float)h7[0];
            a3.y += (float)h6[1] + (float)h7[1];
        }
        for (; t < cnt; ++t) {
            int s0 = __shfl(sv, t);
            f16x2 h0 = H2[(size_t)s0 * 64 + lane];
            a0.x += (float)h0[0];
            a0.y += (float)h0[1];
        }
        j += cnt;
    }
    float dv = dinv[wave];
    float2 acc = {(a0.x + a1.x + a2.x + a3.x) * dv, (a0.y + a1.y + a2.y + a3.y) * dv};
    ((float2*)Hout)[(size_t)wave * 64 + lane] = acc;
}

// ---------- mean-pool split: G*8 partial-sum blocks, then tiny readout ----------
__global__ __launch_bounds__(256) void pool_partial(const float* __restrict__ H,
                                                    const int* __restrict__ gstart,
                                                    float* __restrict__ part) {
    int g = blockIdx.x >> 3, s = blockIdx.x & 7;
    int tid = threadIdx.x;
    int f = tid & 127, half = tid >> 7;
    int s0 = gstart[g], e0 = gstart[g + 1];
    int len = e0 - s0;
    int chunk = (len + 7) >> 3;
    int rs = s0 + s * chunk;
    int re = rs + chunk; if (re > e0) re = e0;
    float sum = 0.f;
    for (int n = rs + half; n < re; n += 2)
        sum += H[(size_t)n * C_HID + f];
    part[(size_t)blockIdx.x * 256 + tid] = sum;
}

__global__ __launch_bounds__(256) void pool_readout(const float* __restrict__ part, const int* __restrict__ gstart,
                                                    const float* __restrict__ B, void* __restrict__ out,
                                                    const int* __restrict__ flagp) {
    __shared__ float phi[2048];
    __shared__ float red[256];
    __shared__ float partl[8][32];
    const int is_f32 = *flagp;
    int g = blockIdx.x;
    int tid = threadIdx.x;
    float sum = 0.f;
#pragma unroll
    for (int s = 0; s < 8; ++s)
        sum += part[((size_t)g * 8 + s) * 256 + tid];
    red[tid] = sum;
    __syncthreads();
    if (tid < 128) {
        int s0 = gstart[g], e0 = gstart[g + 1];
        float cnt = fmaxf((float)(e0 - s0), 1.0f);
        float x = (red[tid] + red[tid + 128]) / cnt;
        float s1, c1;
        __sincosf(x, &s1, &c1);
        phi[tid * 16 + 0] = c1; phi[tid * 16 + 8] = s1;
        float ck = c1, sk = s1;
#pragma unroll
        for (int h = 1; h < 8; ++h) {
            float cn = ck * c1 - sk * s1;
            float sn = sk * c1 + ck * s1;
            phi[tid * 16 + h] = cn; phi[tid * 16 + 8 + h] = sn;
            ck = cn; sk = sn;
        }
    }
    __syncthreads();
    int o = tid & 31, p = tid >> 5;
    float acc = 0.f;
    for (int k = p * 256; k < p * 256 + 256; ++k)
        acc = fmaf(phi[k], B[k * C_LAT + o], acc);
    partl[p][o] = acc;
    __syncthreads();
    if (tid < 32) {
        float s = 0.f;
#pragma unroll
        for (int pp = 0; pp < 8; ++pp) s += partl[pp][tid];
        if (is_f32) ((float*)out)[g * C_LAT + tid] = s;
        else        ((bf16*)out)[g * C_LAT + tid] = __float2bfloat16(s);
    }
}

extern "C" void kernel_launch(void* const* d_in, const int* in_sizes, int n_in,
                              void* d_out, int out_size, void* d_ws, size_t ws_size,
                              hipStream_t stream) {
    const void* features = d_in[0];
    const int*  edge     = (const int*)d_in[1];
    const int*  batch    = (const int*)d_in[2];
    const void* W_embed  = d_in[3];
    const void* W_mp     = d_in[4];
    const void* W_read   = d_in[5];

    const int N = in_sizes[0] / C_IN;
    const int E = in_sizes[1] / 2;
    const int* row = edge;
    const int* col = edge + E;
    const int nScanBlocks = (N + 1023) / 1024;
    const bool packed_ok = (N <= 65536);

    char* ws = (char*)d_ws;
    auto alloc = [&](size_t bytes) { char* p = ws; ws += (bytes + 255) & ~(size_t)255; return p; };
    float* h_a    = (float*)alloc((size_t)N * C_HID * 4);
    f16*   h16    = (f16*)alloc((size_t)N * C_HID * 2);
    f16*   Bte    = (f16*)alloc((size_t)16 * 4 * 256 * 8 * 2);          // 256 KB
    f16*   Btmp   = (f16*)alloc((size_t)C_L * 32 * 4 * 256 * 8 * 2);    // 1.5 MB
    float* Brd    = (float*)alloc((size_t)2048 * C_LAT * 4);
    float* ppart  = (float*)alloc((size_t)C_G * 8 * 256 * 4);           // 512 KB
    int*   deg    = (int*)alloc((size_t)N * 4);
    float* dinv   = (float*)alloc((size_t)N * 4);
    int*   rowptr = (int*)alloc((size_t)(N + 1) * 4);
    int*   cursor = (int*)alloc((size_t)N * 4);
    unsigned short* srcs16 = (unsigned short*)alloc((size_t)(E + N) * 2);
    int*   srcs32 = (int*)alloc(packed_ok ? 256 : (size_t)(E + N) * 4);
    int*   bsum   = (int*)alloc((size_t)nScanBlocks * 4);
    int*   gstart = (int*)alloc((size_t)(C_G + 1) * 4);
    int*   dflag  = (int*)alloc(256);

    hipMemsetAsync(deg, 0, (size_t)N * 4, stream);
    hipMemsetAsync(cursor, 0, (size_t)N * 4, stream);

    detect_dtype<<<1, 256, 0, stream>>>((const unsigned short*)W_embed, dflag);

    repack_embed<<<(16 * 4 * 256 * 8 + 255) / 256, 256, 0, stream>>>(W_embed, Bte, dflag);
    repack_mp<<<(C_L * 32 * 4 * 256 * 8 + 255) / 256, 256, 0, stream>>>(W_mp, Btmp, dflag);
    repack_read<<<(2 * C_LAT * C_HID * C_H + 255) / 256, 256, 0, stream>>>(W_read, Brd, dflag);

    deg_count<<<(E + N + 255) / 256, 256, 0, stream>>>(col, deg, E, N);
    dinv_kernel<<<(N + 255) / 256, 256, 0, stream>>>(deg, dinv, N);
    graph_bounds<<<1, 128, 0, stream>>>(batch, gstart, N);
    scan1<<<nScanBlocks, 1024, 0, stream>>>(deg, rowptr, bsum, N);
    scan2<<<1, 64, 0, stream>>>(bsum, nScanBlocks);
    scan3<<<nScanBlocks, 1024, 0, stream>>>(rowptr, bsum, N);
    if (packed_ok) {
        const int nchunks = 256;
        csr_fill_part<<<nchunks * 8, 256, 0, stream>>>(row, col, rowptr, cursor, srcs16, E, N, nchunks);
    } else {
        csr_fill<<<(E + N + 255) / 256, 256, 0, stream>>>(row, col, rowptr, cursor, srcs32, E, N);
    }

    const int gemm_grid = (N + 63) / 64;
    kan_gemm_mfma<C_IN, false><<<gemm_grid, 256, 0, stream>>>(features, Bte, h_a, nullptr, nullptr, N, dflag);
    for (int l = 0; l < C_L; ++l) {
        kan_gemm_mfma<C_HID, true><<<gemm_grid, 256, 0, stream>>>(h_a, Btmp + (size_t)l * 32 * 4 * 256 * 8,
                                                                  nullptr, h16, dinv, N, nullptr);
        if (packed_ok)
            aggregate<unsigned short><<<((size_t)N * 64 + 255) / 256, 256, 0, stream>>>(h16, h_a, rowptr, srcs16, dinv, N);
        else
            aggregate<int><<<((size_t)N * 64 + 255) / 256, 256, 0, stream>>>(h16, h_a, rowptr, srcs32, dinv, N);
    }

    pool_partial<<<C_G * 8, 256, 0, stream>>>(h_a, gstart, ppart);
    pool_readout<<<C_G, 256, 0, stream>>>(ppart, gstart, Brd, d_out, dflag);
}

// Round 10
// 573.380 us; speedup vs baseline: 2.5096x; 1.0005x over previous
//
#include <hip/hip_runtime.h>
#include <hip/hip_bf16.h>
#include <cstdint>

typedef __hip_bfloat16 bf16;
typedef _Float16 f16;
typedef f16 f16x2 __attribute__((ext_vector_type(2)));
typedef f16 f16x4 __attribute__((ext_vector_type(4)));
typedef f16 f16x8 __attribute__((ext_vector_type(8)));
typedef float f32x4 __attribute__((ext_vector_type(4)));

#define C_IN   64
#define C_HID  128
#define C_LAT  32
#define C_H    8
#define C_L    3
#define C_G    64

// Runtime input-dtype handling (harness may hand fp32 or bf16). flag==1 -> fp32.
__device__ inline float load_in(const void* p, size_t idx, int is_f32) {
    if (is_f32) return ((const float*)p)[idx];
    return __bfloat162float(((const bf16*)p)[idx]);
}

__global__ void detect_dtype(const unsigned short* __restrict__ W, int* __restrict__ flag) {
    __shared__ int cnt;
    if (threadIdx.x == 0) cnt = 0;
    __syncthreads();
    int local = 0;
    for (int i = threadIdx.x; i < 8192; i += 256) {
        int e = (W[i] >> 7) & 0xFF;
        if (e >= 135) local++;
    }
    atomicAdd(&cnt, local);
    __syncthreads();
    if (threadIdx.x == 0) *flag = (cnt > 64) ? 1 : 0;
}

// ---------- weight repack -> fragment-major single-f16 layout (v9, verified) ----------
// B[((s*4 + j)*256 + t)*8 + e], j = kc*2 + nt
// frag(j,t): o = w*32 + nt*16 + l16;  kglob = s*64 + kc*32 + quad*8 + e
__global__ void repack_embed(const void* __restrict__ W, f16* __restrict__ B,
                             const int* __restrict__ flagp) {
    const int is_f32 = *flagp;
    int idx = blockIdx.x * blockDim.x + threadIdx.x;
    if (idx >= 16 * 4 * 256 * 8) return;          // 131072 f16
    int e = idx & 7;
    int t = (idx >> 3) & 255;
    int j = (idx >> 11) & 3;
    int s = idx >> 13;
    int w = t >> 6, lane = t & 63, quad = lane >> 4, l16 = lane & 15;
    int kc = j >> 1, nt = j & 1;
    int o  = w * 32 + nt * 16 + l16;
    int kg = s * 64 + kc * 32 + quad * 8 + e;
    int i = kg >> 4, trig = (kg >> 3) & 1, h = kg & 7;
    int widx = ((trig * C_HID + o) * C_IN + i) * C_H + h;
    B[idx] = (f16)load_in(W, widx, is_f32);
}

__global__ void repack_mp(const void* __restrict__ W, f16* __restrict__ B,
                          const int* __restrict__ flagp) {
    const int is_f32 = *flagp;
    int idx = blockIdx.x * blockDim.x + threadIdx.x;
    if (idx >= C_L * 32 * 4 * 256 * 8) return;    // 786432 f16
    int e = idx & 7;
    int t = (idx >> 3) & 255;
    int j = (idx >> 11) & 3;
    int s = (idx >> 13) & 31;
    int l = idx >> 18;
    int w = t >> 6, lane = t & 63, quad = lane >> 4, l16 = lane & 15;
    int kc = j >> 1, nt = j & 1;
    int o  = w * 32 + nt * 16 + l16;
    int kg = s * 64 + kc * 32 + quad * 8 + e;
    int i = kg >> 4, trig = (kg >> 3) & 1, h = kg & 7;
    int widx = (((l * 2 + trig) * C_HID + o) * C_HID + i) * C_H + h;
    B[idx] = (f16)load_in(W, widx, is_f32);
}

// readout weights stay fp32 (tiny GEMM)
__global__ void repack_read(const void* __restrict__ W, float* __restrict__ B, const int* __restrict__ flagp) {
    const int is_f32 = *flagp;
    int idx = blockIdx.x * blockDim.x + threadIdx.x;
    if (idx >= 2 * C_LAT * C_HID * C_H) return;
    int h = idx & 7; int t = idx >> 3;
    int i = t & 127; t >>= 7;
    int o = t & 31; int trig = t >> 5;
    B[(i * 16 + trig * 8 + h) * C_LAT + o] = load_in(W, idx, is_f32);
}

// ---------- graph prep ----------
__global__ void deg_count(const int* __restrict__ col, int* __restrict__ deg, int E, int N) {
    int idx = blockIdx.x * blockDim.x + threadIdx.x;
    if (idx >= E + N) return;
    int c = (idx < E) ? col[idx] : (idx - E);
    atomicAdd(&deg[c], 1);
}

__global__ void dinv_kernel(const int* __restrict__ deg, float* __restrict__ dinv, int N) {
    int n = blockIdx.x * blockDim.x + threadIdx.x;
    if (n >= N) return;
    dinv[n] = rsqrtf((float)deg[n]);   // deg >= 1 (self loop)
}

__global__ void graph_bounds(const int* __restrict__ batch, int* __restrict__ gstart, int N) {
    int g = threadIdx.x;
    if (g > C_G) return;
    int lo = 0, hi = N;
    while (lo < hi) {
        int mid = (lo + hi) >> 1;
        if (batch[mid] < g) lo = mid + 1; else hi = mid;
    }
    gstart[g] = lo;
}

// ---------- hierarchical exclusive scan of deg -> rowptr ----------
__global__ void scan1(const int* __restrict__ deg, int* __restrict__ rowptr,
                      int* __restrict__ bsum, int N) {
    __shared__ int sdata[1024];
    int i = blockIdx.x * 1024 + threadIdx.x;
    int v = (i < N) ? deg[i] : 0;
    sdata[threadIdx.x] = v;
    __syncthreads();
    for (int off = 1; off < 1024; off <<= 1) {
        int t = (threadIdx.x >= (unsigned)off) ? sdata[threadIdx.x - off] : 0;
        __syncthreads();
        sdata[threadIdx.x] += t;
        __syncthreads();
    }
    if (i < N) rowptr[i + 1] = sdata[threadIdx.x];
    if (threadIdx.x == 1023) bsum[blockIdx.x] = sdata[1023];
}

__global__ void scan2(int* __restrict__ bsum, int nb) {
    if (threadIdx.x == 0) {
        int acc = 0;
        for (int i = 0; i < nb; ++i) { int t = bsum[i]; bsum[i] = acc; acc += t; }
    }
}

__global__ void scan3(int* __restrict__ rowptr, const int* __restrict__ bsum, int N) {
    int i = blockIdx.x * 1024 + threadIdx.x;
    if (i < N) rowptr[i + 1] += bsum[blockIdx.x];
    if (i == 0) rowptr[0] = 0;
}

// ---------- CSR fill: XCD-confined filtered multi-sweep (v7) ----------
// NOTE (r9): WRITE_SIZE still ~60 MB (L2-level churn; TCC counters are L2, not HBM).
// Confinement theory partially falsified — u16+parallelism gave the 120->78 win.
// Left as-is; further gains need a verified block->XCD probe first.
__global__ __launch_bounds__(256) void csr_fill_part(const int* __restrict__ row, const int* __restrict__ col,
                                                     const int* __restrict__ rowptr, int* __restrict__ cursor,
                                                     unsigned short* __restrict__ srcs, int E, int N,
                                                     int nchunks) {
    int grp = blockIdx.x & 7;
    int chunk = blockIdx.x >> 3;
    int rsz = (N + 7) >> 3;
    int lo = grp * rsz;
    int hi = lo + rsz; if (hi > N) hi = N;
    int total = E + N;
    int per = (total + nchunks - 1) / nchunks;
    int start = chunk * per;
    int stop = start + per; if (stop > total) stop = total;
    for (int idx = start + threadIdx.x; idx < stop; idx += 256) {
        int r, c;
        if (idx < E) { r = row[idx]; c = col[idx]; } else { r = c = idx - E; }
        if (c >= lo && c < hi) {
            int pos = rowptr[c] + atomicAdd(&cursor[c], 1);
            srcs[pos] = (unsigned short)r;
        }
    }
}

// fallback (N > 65536): original int-scatter path
__global__ void csr_fill(const int* __restrict__ row, const int* __restrict__ col,
                         const int* __restrict__ rowptr, int* __restrict__ cursor,
                         int* __restrict__ srcs, int E, int N) {
    int idx = blockIdx.x * blockDim.x + threadIdx.x;
    if (idx >= E + N) return;
    int r, c;
    if (idx < E) { r = row[idx]; c = col[idx]; } else { r = c = idx - E; }
    int pos = rowptr[c] + atomicAdd(&cursor[c], 1);
    srcs[pos] = r;
}

// ---------- Phi (plain f16) into XOR-swizzled [64][64] A-tile ----------
__device__ inline void phi_write(f16* __restrict__ Ah, int offC, int offS, float x) {
    float c[8], s[8];
    __sincosf(x, &s[0], &c[0]);
    float t2 = 2.f * c[0];
    c[1] = t2 * c[0] - 1.f;
    s[1] = t2 * s[0];
#pragma unroll
    for (int h = 2; h < 8; ++h) {
        c[h] = t2 * c[h-1] - c[h-2];
        s[h] = t2 * s[h-1] - s[h-2];
    }
    f16x8 ch, sh;
#pragma unroll
    for (int h = 0; h < 8; ++h) { ch[h] = (f16)c[h]; sh[h] = (f16)s[h]; }
    *(f16x8*)&Ah[offC] = ch;
    *(f16x8*)&Ah[offS] = sh;
}

// ---------- fused-Phi GEMM: Y[M,128] = Phi(X)[M, INF*16] x B^T (v9 structure) ----------
#define STAGE_BODY(S, BC, BN, ACUR, ANXT)                                             \
  {                                                                                    \
    const int s_ = (S);                                                                \
    if (s_ + 1 < NST) {                                                                \
      _Pragma("unroll")                                                                \
      for (int j = 0; j < 4; ++j)                                                      \
        BN[j] = Bf[((size_t)(s_ + 1) * 4 + j) * 256 + tid];                            \
    }                                                                                  \
    float xf_ = 0.f;                                                                   \
    if (s_ + 2 < NST && rowok)                                                         \
      xf_ = load_in(X, (size_t)gm * INF + (s_ + 2) * 4 + pf, is_f32);                  \
    if (s_ + 1 < NST)                                                                  \
      phi_write(ANXT, offC, offS, xn);                                                 \
    _Pragma("unroll")                                                                  \
    for (int kc = 0; kc < 2; ++kc) {                                                   \
      f16x8 ah[4];                                                                     \
      _Pragma("unroll")                                                                \
      for (int mt = 0; mt < 4; ++mt) {                                                 \
        int ro = (mt * 16 + l16) * 64 + (((kc * 4 + quad) ^ (l16 & 7)) * 8);           \
        ah[mt] = *(const f16x8*)&ACUR[ro];                                             \
      }                                                                                \
      __builtin_amdgcn_s_setprio(1);                                                   \
      _Pragma("unroll")                                                                \
      for (int mt = 0; mt < 4; ++mt)                                                   \
        _Pragma("unroll")                                                              \
        for (int nt = 0; nt < 2; ++nt)                                                 \
          acc[mt][nt] = __builtin_amdgcn_mfma_f32_16x16x32_f16(ah[mt], BC[kc*2+nt], acc[mt][nt], 0, 0, 0); \
      __builtin_amdgcn_s_setprio(0);                                                   \
    }                                                                                  \
    __syncthreads();                                                                   \
    xn = xf_;                                                                          \
  }

template<int INF, bool F16OUT>
__global__ __launch_bounds__(256, 4) void kan_gemm_mfma(const void* __restrict__ X,
                                                        const f16* __restrict__ Bt,
                                                        float* __restrict__ Yf, f16* __restrict__ Yh,
                                                        const float* __restrict__ dinv,
                                                        int M, const int* __restrict__ flagp) {
    constexpr int NST = INF / 4;     // stages of K=64 (4 input features each)
    __shared__ f16 AhB[2][64 * 64];
    __shared__ float dinvs[64];
    const int is_f32 = flagp ? *flagp : 1;
    const int tid  = threadIdx.x;
    const int m0   = blockIdx.x * 64;
    const int w    = tid >> 6, lane = tid & 63;
    const int quad = lane >> 4, l16 = lane & 15;

    const int pf   = w;
    const int gm   = m0 + lane;
    const bool rowok = gm < M;
    const int offC = lane * 64 + (((w * 2)     ^ (lane & 7)) * 8);
    const int offS = lane * 64 + (((w * 2 + 1) ^ (lane & 7)) * 8);

    if (F16OUT && tid < 64) dinvs[tid] = (m0 + tid < M) ? dinv[m0 + tid] : 0.f;

    f32x4 acc[4][2] = {};
    const f16x8* __restrict__ Bf = (const f16x8*)Bt;

    f16x8 b0[4], b1[4];
#pragma unroll
    for (int j = 0; j < 4; ++j) b0[j] = Bf[(size_t)j * 256 + tid];

    float x0 = rowok ? load_in(X, (size_t)gm * INF + pf, is_f32) : 0.f;
    float xn = (NST > 1 && rowok) ? load_in(X, (size_t)gm * INF + 4 + pf, is_f32) : 0.f;

    phi_write(AhB[0], offC, offS, x0);
    __syncthreads();

    for (int s = 0; s < NST; s += 2) {
        STAGE_BODY(s,     b0, b1, AhB[0], AhB[1]);
        STAGE_BODY(s + 1, b1, b0, AhB[1], AhB[0]);
    }

    // C/D layout: col = lane&15, row = quad*4 + reg
#pragma unroll
    for (int mt = 0; mt < 4; ++mt) {
        int rloc = mt * 16 + quad * 4;
#pragma unroll
        for (int nt = 0; nt < 2; ++nt) {
            int cn = w * 32 + nt * 16 + l16;
#pragma unroll
            for (int r = 0; r < 4; ++r) {
                int m = m0 + rloc + r;
                if (m < M) {
                    if (F16OUT) Yh[(size_t)m * 128 + cn] = (f16)(acc[mt][nt][r] * dinvs[rloc + r]);
                    else        Yf[(size_t)m * 128 + cn] = acc[mt][nt][r];
                }
            }
        }
    }
}

// ---------- CSR aggregation v3: two rows per gather instruction ----------
// r5 showed MLP-depth neutral -> issue-bound. Lanes 0-31 read even rows' 128 feats
// as f16x4 (8 B/lane), lanes 32-63 odd rows: one VMEM instr covers TWO rows (512 B).
// Halves gather + shuffle instruction count at identical bytes and MLP (4 loads =
// 8 rows in flight). Halves combined at the end via shfl_xor(32). f32 reassociation
// only (even/odd source split).
template<typename IT>
__global__ __launch_bounds__(256) void aggregate(const f16* __restrict__ Hin, float* __restrict__ Hout,
                                                 const int* __restrict__ rowptr, const IT* __restrict__ srcs,
                                                 const float* __restrict__ dinv, int N) {
    int wave = (int)((blockIdx.x * blockDim.x + threadIdx.x) >> 6);
    int lane = threadIdx.x & 63;
    if (wave >= N) return;
    const f16x4* H4 = (const f16x4*)Hin;
    const int half = lane >> 5;          // 0: even-index rows, 1: odd-index rows
    const int fpos = lane & 31;          // features fpos*4 .. fpos*4+3
    int beg = rowptr[wave], end = rowptr[wave + 1];
    f32x4 a0 = {0.f,0.f,0.f,0.f}, a1 = {0.f,0.f,0.f,0.f};
    f32x4 a2 = {0.f,0.f,0.f,0.f}, a3 = {0.f,0.f,0.f,0.f};
    int j = beg;
    while (j < end) {
        int cnt = end - j; if (cnt > 64) cnt = 64;
        int sv = (lane < cnt) ? (int)srcs[j + lane] : 0;
        int t = 0;
        for (; t + 8 <= cnt; t += 8) {
            int sA = __shfl(sv, t + 0 + half);
            int sB = __shfl(sv, t + 2 + half);
            int sC = __shfl(sv, t + 4 + half);
            int sD = __shfl(sv, t + 6 + half);
            // 4 gathers = 8 rows in flight (2 KB)
            f16x4 hA = H4[(size_t)sA * 32 + fpos];
            f16x4 hB = H4[(size_t)sB * 32 + fpos];
            f16x4 hC = H4[(size_t)sC * 32 + fpos];
            f16x4 hD = H4[(size_t)sD * 32 + fpos];
#pragma unroll
            for (int q = 0; q < 4; ++q) {
                a0[q] += (float)hA[q];
                a1[q] += (float)hB[q];
                a2[q] += (float)hC[q];
                a3[q] += (float)hD[q];
            }
        }
        for (; t + 2 <= cnt; t += 2) {
            int sA = __shfl(sv, t + half);
            f16x4 hA = H4[(size_t)sA * 32 + fpos];
#pragma unroll
            for (int q = 0; q < 4; ++q) a0[q] += (float)hA[q];
        }
        if (t < cnt) {                    // odd single: both halves load, only half 0 adds
            int sA = __shfl(sv, t);
            f16x4 hA = H4[(size_t)sA * 32 + fpos];
            if (half == 0) {
#pragma unroll
                for (int q = 0; q < 4; ++q) a0[q] += (float)hA[q];
            }
        }
        j += cnt;
    }
    float dv = dinv[wave];
    f32x4 a;
#pragma unroll
    for (int q = 0; q < 4; ++q) {
        float v = a0[q] + a1[q] + a2[q] + a3[q];
        v += __shfl_xor(v, 32);
        a[q] = v * dv;
    }
    if (half == 0)
        ((f32x4*)Hout)[(size_t)wave * 32 + fpos] = a;
}

// ---------- mean-pool split: G*8 partial-sum blocks, then tiny readout ----------
__global__ __launch_bounds__(256) void pool_partial(const float* __restrict__ H,
                                                    const int* __restrict__ gstart,
                                                    float* __restrict__ part) {
    int g = blockIdx.x >> 3, s = blockIdx.x & 7;
    int tid = threadIdx.x;
    int f = tid & 127, half = tid >> 7;
    int s0 = gstart[g], e0 = gstart[g + 1];
    int len = e0 - s0;
    int chunk = (len + 7) >> 3;
    int rs = s0 + s * chunk;
    int re = rs + chunk; if (re > e0) re = e0;
    float sum = 0.f;
    for (int n = rs + half; n < re; n += 2)
        sum += H[(size_t)n * C_HID + f];
    part[(size_t)blockIdx.x * 256 + tid] = sum;
}

__global__ __launch_bounds__(256) void pool_readout(const float* __restrict__ part, const int* __restrict__ gstart,
                                                    const float* __restrict__ B, void* __restrict__ out,
                                                    const int* __restrict__ flagp) {
    __shared__ float phi[2048];
    __shared__ float red[256];
    __shared__ float partl[8][32];
    const int is_f32 = *flagp;
    int g = blockIdx.x;
    int tid = threadIdx.x;
    float sum = 0.f;
#pragma unroll
    for (int s = 0; s < 8; ++s)
        sum += part[((size_t)g * 8 + s) * 256 + tid];
    red[tid] = sum;
    __syncthreads();
    if (tid < 128) {
        int s0 = gstart[g], e0 = gstart[g + 1];
        float cnt = fmaxf((float)(e0 - s0), 1.0f);
        float x = (red[tid] + red[tid + 128]) / cnt;
        float s1, c1;
        __sincosf(x, &s1, &c1);
        phi[tid * 16 + 0] = c1; phi[tid * 16 + 8] = s1;
        float ck = c1, sk = s1;
#pragma unroll
        for (int h = 1; h < 8; ++h) {
            float cn = ck * c1 - sk * s1;
            float sn = sk * c1 + ck * s1;
            phi[tid * 16 + h] = cn; phi[tid * 16 + 8 + h] = sn;
            ck = cn; sk = sn;
        }
    }
    __syncthreads();
    int o = tid & 31, p = tid >> 5;
    float acc = 0.f;
    for (int k = p * 256; k < p * 256 + 256; ++k)
        acc = fmaf(phi[k], B[k * C_LAT + o], acc);
    partl[p][o] = acc;
    __syncthreads();
    if (tid < 32) {
        float s = 0.f;
#pragma unroll
        for (int pp = 0; pp < 8; ++pp) s += partl[pp][tid];
        if (is_f32) ((float*)out)[g * C_LAT + tid] = s;
        else        ((bf16*)out)[g * C_LAT + tid] = __float2bfloat16(s);
    }
}

extern "C" void kernel_launch(void* const* d_in, const int* in_sizes, int n_in,
                              void* d_out, int out_size, void* d_ws, size_t ws_size,
                              hipStream_t stream) {
    const void* features = d_in[0];
    const int*  edge     = (const int*)d_in[1];
    const int*  batch    = (const int*)d_in[2];
    const void* W_embed  = d_in[3];
    const void* W_mp     = d_in[4];
    const void* W_read   = d_in[5];

    const int N = in_sizes[0] / C_IN;
    const int E = in_sizes[1] / 2;
    const int* row = edge;
    const int* col = edge + E;
    const int nScanBlocks = (N + 1023) / 1024;
    const bool packed_ok = (N <= 65536);

    char* ws = (char*)d_ws;
    auto alloc = [&](size_t bytes) { char* p = ws; ws += (bytes + 255) & ~(size_t)255; return p; };
    float* h_a    = (float*)alloc((size_t)N * C_HID * 4);
    f16*   h16    = (f16*)alloc((size_t)N * C_HID * 2);
    f16*   Bte    = (f16*)alloc((size_t)16 * 4 * 256 * 8 * 2);          // 256 KB
    f16*   Btmp   = (f16*)alloc((size_t)C_L * 32 * 4 * 256 * 8 * 2);    // 1.5 MB
    float* Brd    = (float*)alloc((size_t)2048 * C_LAT * 4);
    float* ppart  = (float*)alloc((size_t)C_G * 8 * 256 * 4);           // 512 KB
    int*   deg    = (int*)alloc((size_t)N * 4);
    float* dinv   = (float*)alloc((size_t)N * 4);
    int*   rowptr = (int*)alloc((size_t)(N + 1) * 4);
    int*   cursor = (int*)alloc((size_t)N * 4);
    unsigned short* srcs16 = (unsigned short*)alloc((size_t)(E + N) * 2);
    int*   srcs32 = (int*)alloc(packed_ok ? 256 : (size_t)(E + N) * 4);
    int*   bsum   = (int*)alloc((size_t)nScanBlocks * 4);
    int*   gstart = (int*)alloc((size_t)(C_G + 1) * 4);
    int*   dflag  = (int*)alloc(256);

    hipMemsetAsync(deg, 0, (size_t)N * 4, stream);
    hipMemsetAsync(cursor, 0, (size_t)N * 4, stream);

    detect_dtype<<<1, 256, 0, stream>>>((const unsigned short*)W_embed, dflag);

    repack_embed<<<(16 * 4 * 256 * 8 + 255) / 256, 256, 0, stream>>>(W_embed, Bte, dflag);
    repack_mp<<<(C_L * 32 * 4 * 256 * 8 + 255) / 256, 256, 0, stream>>>(W_mp, Btmp, dflag);
    repack_read<<<(2 * C_LAT * C_HID * C_H + 255) / 256, 256, 0, stream>>>(W_read, Brd, dflag);

    deg_count<<<(E + N + 255) / 256, 256, 0, stream>>>(col, deg, E, N);
    dinv_kernel<<<(N + 255) / 256, 256, 0, stream>>>(deg, dinv, N);
    graph_bounds<<<1, 128, 0, stream>>>(batch, gstart, N);
    scan1<<<nScanBlocks, 1024, 0, stream>>>(deg, rowptr, bsum, N);
    scan2<<<1, 64, 0, stream>>>(bsum, nScanBlocks);
    scan3<<<nScanBlocks, 1024, 0, stream>>>(rowptr, bsum, N);
    if (packed_ok) {
        const int nchunks = 256;
        csr_fill_part<<<nchunks * 8, 256, 0, stream>>>(row, col, rowptr, cursor, srcs16, E, N, nchunks);
    } else {
        csr_fill<<<(E + N + 255) / 256, 256, 0, stream>>>(row, col, rowptr, cursor, srcs32, E, N);
    }

    const int gemm_grid = (N + 63) / 64;
    kan_gemm_mfma<C_IN, false><<<gemm_grid, 256, 0, stream>>>(features, Bte, h_a, nullptr, nullptr, N, dflag);
    for (int l = 0; l < C_L; ++l) {
        kan_gemm_mfma<C_HID, true><<<gemm_grid, 256, 0, stream>>>(h_a, Btmp + (size_t)l * 32 * 4 * 256 * 8,
                                                                  nullptr, h16, dinv, N, nullptr);
        if (packed_ok)
            aggregate<unsigned short><<<((size_t)N * 64 + 255) / 256, 256, 0, stream>>>(h16, h_a, rowptr, srcs16, dinv, N);
        else
            aggregate<int><<<((size_t)N * 64 + 255) / 256, 256, 0, stream>>>(h16, h_a, rowptr, srcs32, dinv, N);
    }

    pool_partial<<<C_G * 8, 256, 0, stream>>>(h_a, gstart, ppart);
    pool_readout<<<C_G, 256, 0, stream>>>(ppart, gstart, Brd, d_out, dflag);
}

// Round 11
// 572.872 us; speedup vs baseline: 2.5119x; 1.0009x over previous
//
#include <hip/hip_runtime.h>
#include <hip/hip_bf16.h>
#include <cstdint>

typedef __hip_bfloat16 bf16;
typedef _Float16 f16;
typedef f16 f16x2 __attribute__((ext_vector_type(2)));
typedef f16 f16x4 __attribute__((ext_vector_type(4)));
typedef f16 f16x8 __attribute__((ext_vector_type(8)));
typedef float f32x4 __attribute__((ext_vector_type(4)));

#define C_IN   64
#define C_HID  128
#define C_LAT  32
#define C_H    8
#define C_L    3
#define C_G    64

// Runtime input-dtype handling (harness may hand fp32 or bf16). flag==1 -> fp32.
__device__ inline float load_in(const void* p, size_t idx, int is_f32) {
    if (is_f32) return ((const float*)p)[idx];
    return __bfloat162float(((const bf16*)p)[idx]);
}

__global__ void detect_dtype(const unsigned short* __restrict__ W, int* __restrict__ flag) {
    __shared__ int cnt;
    if (threadIdx.x == 0) cnt = 0;
    __syncthreads();
    int local = 0;
    for (int i = threadIdx.x; i < 8192; i += 256) {
        int e = (W[i] >> 7) & 0xFF;
        if (e >= 135) local++;
    }
    atomicAdd(&cnt, local);
    __syncthreads();
    if (threadIdx.x == 0) *flag = (cnt > 64) ? 1 : 0;
}

// ---------- weight repack -> fragment-major single-f16 layout (v9, verified) ----------
// B[((s*4 + j)*256 + t)*8 + e], j = kc*2 + nt
// frag(j,t): o = w*32 + nt*16 + l16;  kglob = s*64 + kc*32 + quad*8 + e
__global__ void repack_embed(const void* __restrict__ W, f16* __restrict__ B,
                             const int* __restrict__ flagp) {
    const int is_f32 = *flagp;
    int idx = blockIdx.x * blockDim.x + threadIdx.x;
    if (idx >= 16 * 4 * 256 * 8) return;          // 131072 f16
    int e = idx & 7;
    int t = (idx >> 3) & 255;
    int j = (idx >> 11) & 3;
    int s = idx >> 13;
    int w = t >> 6, lane = t & 63, quad = lane >> 4, l16 = lane & 15;
    int kc = j >> 1, nt = j & 1;
    int o  = w * 32 + nt * 16 + l16;
    int kg = s * 64 + kc * 32 + quad * 8 + e;
    int i = kg >> 4, trig = (kg >> 3) & 1, h = kg & 7;
    int widx = ((trig * C_HID + o) * C_IN + i) * C_H + h;
    B[idx] = (f16)load_in(W, widx, is_f32);
}

__global__ void repack_mp(const void* __restrict__ W, f16* __restrict__ B,
                          const int* __restrict__ flagp) {
    const int is_f32 = *flagp;
    int idx = blockIdx.x * blockDim.x + threadIdx.x;
    if (idx >= C_L * 32 * 4 * 256 * 8) return;    // 786432 f16
    int e = idx & 7;
    int t = (idx >> 3) & 255;
    int j = (idx >> 11) & 3;
    int s = (idx >> 13) & 31;
    int l = idx >> 18;
    int w = t >> 6, lane = t & 63, quad = lane >> 4, l16 = lane & 15;
    int kc = j >> 1, nt = j & 1;
    int o  = w * 32 + nt * 16 + l16;
    int kg = s * 64 + kc * 32 + quad * 8 + e;
    int i = kg >> 4, trig = (kg >> 3) & 1, h = kg & 7;
    int widx = (((l * 2 + trig) * C_HID + o) * C_HID + i) * C_H + h;
    B[idx] = (f16)load_in(W, widx, is_f32);
}

// readout weights stay fp32 (tiny GEMM)
__global__ void repack_read(const void* __restrict__ W, float* __restrict__ B, const int* __restrict__ flagp) {
    const int is_f32 = *flagp;
    int idx = blockIdx.x * blockDim.x + threadIdx.x;
    if (idx >= 2 * C_LAT * C_HID * C_H) return;
    int h = idx & 7; int t = idx >> 3;
    int i = t & 127; t >>= 7;
    int o = t & 31; int trig = t >> 5;
    B[(i * 16 + trig * 8 + h) * C_LAT + o] = load_in(W, idx, is_f32);
}

// ---------- graph prep ----------
__global__ void deg_count(const int* __restrict__ col, int* __restrict__ deg, int E, int N) {
    int idx = blockIdx.x * blockDim.x + threadIdx.x;
    if (idx >= E + N) return;
    int c = (idx < E) ? col[idx] : (idx - E);
    atomicAdd(&deg[c], 1);
}

__global__ void dinv_kernel(const int* __restrict__ deg, float* __restrict__ dinv, int N) {
    int n = blockIdx.x * blockDim.x + threadIdx.x;
    if (n >= N) return;
    dinv[n] = rsqrtf((float)deg[n]);   // deg >= 1 (self loop)
}

__global__ void graph_bounds(const int* __restrict__ batch, int* __restrict__ gstart, int N) {
    int g = threadIdx.x;
    if (g > C_G) return;
    int lo = 0, hi = N;
    while (lo < hi) {
        int mid = (lo + hi) >> 1;
        if (batch[mid] < g) lo = mid + 1; else hi = mid;
    }
    gstart[g] = lo;
}

// ---------- hierarchical exclusive scan of deg -> rowptr ----------
__global__ void scan1(const int* __restrict__ deg, int* __restrict__ rowptr,
                      int* __restrict__ bsum, int N) {
    __shared__ int sdata[1024];
    int i = blockIdx.x * 1024 + threadIdx.x;
    int v = (i < N) ? deg[i] : 0;
    sdata[threadIdx.x] = v;
    __syncthreads();
    for (int off = 1; off < 1024; off <<= 1) {
        int t = (threadIdx.x >= (unsigned)off) ? sdata[threadIdx.x - off] : 0;
        __syncthreads();
        sdata[threadIdx.x] += t;
        __syncthreads();
    }
    if (i < N) rowptr[i + 1] = sdata[threadIdx.x];
    if (threadIdx.x == 1023) bsum[blockIdx.x] = sdata[1023];
}

__global__ void scan2(int* __restrict__ bsum, int nb) {
    if (threadIdx.x == 0) {
        int acc = 0;
        for (int i = 0; i < nb; ++i) { int t = bsum[i]; bsum[i] = acc; acc += t; }
    }
}

__global__ void scan3(int* __restrict__ rowptr, const int* __restrict__ bsum, int N) {
    int i = blockIdx.x * 1024 + threadIdx.x;
    if (i < N) rowptr[i + 1] += bsum[blockIdx.x];
    if (i == 0) rowptr[0] = 0;
}

// ---------- CSR fill: XCD-confined filtered multi-sweep + NON-TEMPORAL stream ----------
// v11 theory (r10 counters): WRITE 60 MB = the 13 MB/sweep edge STREAM evicts the
// group's partially-dirty srcs lines from L2 (~9 evictions/line). Fix: read the edge
// list with __builtin_nontemporal_load (evict-first, no L2 pollution) so dirty srcs
// lines stay resident until fully written. Predicted WRITE -> <25 MB, dur 77 -> ~50.
__global__ __launch_bounds__(256) void csr_fill_part(const int* __restrict__ row, const int* __restrict__ col,
                                                     const int* __restrict__ rowptr, int* __restrict__ cursor,
                                                     unsigned short* __restrict__ srcs, int E, int N,
                                                     int nchunks) {
    int grp = blockIdx.x & 7;
    int chunk = blockIdx.x >> 3;
    int rsz = (N + 7) >> 3;
    int lo = grp * rsz;
    int hi = lo + rsz; if (hi > N) hi = N;
    int total = E + N;
    int per = (total + nchunks - 1) / nchunks;
    int start = chunk * per;
    int stop = start + per; if (stop > total) stop = total;
    for (int idx = start + threadIdx.x; idx < stop; idx += 256) {
        int r, c;
        if (idx < E) {
            r = __builtin_nontemporal_load(row + idx);
            c = __builtin_nontemporal_load(col + idx);
        } else { r = c = idx - E; }
        if (c >= lo && c < hi) {
            int pos = rowptr[c] + atomicAdd(&cursor[c], 1);
            srcs[pos] = (unsigned short)r;
        }
    }
}

// fallback (N > 65536): original int-scatter path
__global__ void csr_fill(const int* __restrict__ row, const int* __restrict__ col,
                         const int* __restrict__ rowptr, int* __restrict__ cursor,
                         int* __restrict__ srcs, int E, int N) {
    int idx = blockIdx.x * blockDim.x + threadIdx.x;
    if (idx >= E + N) return;
    int r, c;
    if (idx < E) { r = row[idx]; c = col[idx]; } else { r = c = idx - E; }
    int pos = rowptr[c] + atomicAdd(&cursor[c], 1);
    srcs[pos] = r;
}

// ---------- Phi (plain f16) into XOR-swizzled [64][64] A-tile ----------
__device__ inline void phi_write(f16* __restrict__ Ah, int offC, int offS, float x) {
    float c[8], s[8];
    __sincosf(x, &s[0], &c[0]);
    float t2 = 2.f * c[0];
    c[1] = t2 * c[0] - 1.f;
    s[1] = t2 * s[0];
#pragma unroll
    for (int h = 2; h < 8; ++h) {
        c[h] = t2 * c[h-1] - c[h-2];
        s[h] = t2 * s[h-1] - s[h-2];
    }
    f16x8 ch, sh;
#pragma unroll
    for (int h = 0; h < 8; ++h) { ch[h] = (f16)c[h]; sh[h] = (f16)s[h]; }
    *(f16x8*)&Ah[offC] = ch;
    *(f16x8*)&Ah[offS] = sh;
}

// ---------- fused-Phi GEMM: Y[M,128] = Phi(X)[M, INF*16] x B^T (v9 structure) ----------
#define STAGE_BODY(S, BC, BN, ACUR, ANXT)                                             \
  {                                                                                    \
    const int s_ = (S);                                                                \
    if (s_ + 1 < NST) {                                                                \
      _Pragma("unroll")                                                                \
      for (int j = 0; j < 4; ++j)                                                      \
        BN[j] = Bf[((size_t)(s_ + 1) * 4 + j) * 256 + tid];                            \
    }                                                                                  \
    float xf_ = 0.f;                                                                   \
    if (s_ + 2 < NST && rowok)                                                         \
      xf_ = load_in(X, (size_t)gm * INF + (s_ + 2) * 4 + pf, is_f32);                  \
    if (s_ + 1 < NST)                                                                  \
      phi_write(ANXT, offC, offS, xn);                                                 \
    _Pragma("unroll")                                                                  \
    for (int kc = 0; kc < 2; ++kc) {                                                   \
      f16x8 ah[4];                                                                     \
      _Pragma("unroll")                                                                \
      for (int mt = 0; mt < 4; ++mt) {                                                 \
        int ro = (mt * 16 + l16) * 64 + (((kc * 4 + quad) ^ (l16 & 7)) * 8);           \
        ah[mt] = *(const f16x8*)&ACUR[ro];                                             \
      }                                                                                \
      __builtin_amdgcn_s_setprio(1);                                                   \
      _Pragma("unroll")                                                                \
      for (int mt = 0; mt < 4; ++mt)                                                   \
        _Pragma("unroll")                                                              \
        for (int nt = 0; nt < 2; ++nt)                                                 \
          acc[mt][nt] = __builtin_amdgcn_mfma_f32_16x16x32_f16(ah[mt], BC[kc*2+nt], acc[mt][nt], 0, 0, 0); \
      __builtin_amdgcn_s_setprio(0);                                                   \
    }                                                                                  \
    __syncthreads();                                                                   \
    xn = xf_;                                                                          \
  }

template<int INF, bool F16OUT>
__global__ __launch_bounds__(256, 4) void kan_gemm_mfma(const void* __restrict__ X,
                                                        const f16* __restrict__ Bt,
                                                        float* __restrict__ Yf, f16* __restrict__ Yh,
                                                        const float* __restrict__ dinv,
                                                        int M, const int* __restrict__ flagp) {
    constexpr int NST = INF / 4;     // stages of K=64 (4 input features each)
    __shared__ f16 AhB[2][64 * 64];
    __shared__ float dinvs[64];
    const int is_f32 = flagp ? *flagp : 1;
    const int tid  = threadIdx.x;
    const int m0   = blockIdx.x * 64;
    const int w    = tid >> 6, lane = tid & 63;
    const int quad = lane >> 4, l16 = lane & 15;

    const int pf   = w;
    const int gm   = m0 + lane;
    const bool rowok = gm < M;
    const int offC = lane * 64 + (((w * 2)     ^ (lane & 7)) * 8);
    const int offS = lane * 64 + (((w * 2 + 1) ^ (lane & 7)) * 8);

    if (F16OUT && tid < 64) dinvs[tid] = (m0 + tid < M) ? dinv[m0 + tid] : 0.f;

    f32x4 acc[4][2] = {};
    const f16x8* __restrict__ Bf = (const f16x8*)Bt;

    f16x8 b0[4], b1[4];
#pragma unroll
    for (int j = 0; j < 4; ++j) b0[j] = Bf[(size_t)j * 256 + tid];

    float x0 = rowok ? load_in(X, (size_t)gm * INF + pf, is_f32) : 0.f;
    float xn = (NST > 1 && rowok) ? load_in(X, (size_t)gm * INF + 4 + pf, is_f32) : 0.f;

    phi_write(AhB[0], offC, offS, x0);
    __syncthreads();

    for (int s = 0; s < NST; s += 2) {
        STAGE_BODY(s,     b0, b1, AhB[0], AhB[1]);
        STAGE_BODY(s + 1, b1, b0, AhB[1], AhB[0]);
    }

    // C/D layout: col = lane&15, row = quad*4 + reg
#pragma unroll
    for (int mt = 0; mt < 4; ++mt) {
        int rloc = mt * 16 + quad * 4;
#pragma unroll
        for (int nt = 0; nt < 2; ++nt) {
            int cn = w * 32 + nt * 16 + l16;
#pragma unroll
            for (int r = 0; r < 4; ++r) {
                int m = m0 + rloc + r;
                if (m < M) {
                    if (F16OUT) Yh[(size_t)m * 128 + cn] = (f16)(acc[mt][nt][r] * dinvs[rloc + r]);
                    else        Yf[(size_t)m * 128 + cn] = acc[mt][nt][r];
                }
            }
        }
    }
}

// ---------- CSR aggregation v3 (kept; r10 showed issue-rate neutral — gather-BW floor) ----------
template<typename IT>
__global__ __launch_bounds__(256) void aggregate(const f16* __restrict__ Hin, float* __restrict__ Hout,
                                                 const int* __restrict__ rowptr, const IT* __restrict__ srcs,
                                                 const float* __restrict__ dinv, int N) {
    int wave = (int)((blockIdx.x * blockDim.x + threadIdx.x) >> 6);
    int lane = threadIdx.x & 63;
    if (wave >= N) return;
    const f16x4* H4 = (const f16x4*)Hin;
    const int half = lane >> 5;          // 0: even-index rows, 1: odd-index rows
    const int fpos = lane & 31;          // features fpos*4 .. fpos*4+3
    int beg = rowptr[wave], end = rowptr[wave + 1];
    f32x4 a0 = {0.f,0.f,0.f,0.f}, a1 = {0.f,0.f,0.f,0.f};
    f32x4 a2 = {0.f,0.f,0.f,0.f}, a3 = {0.f,0.f,0.f,0.f};
    int j = beg;
    while (j < end) {
        int cnt = end - j; if (cnt > 64) cnt = 64;
        int sv = (lane < cnt) ? (int)srcs[j + lane] : 0;
        int t = 0;
        for (; t + 8 <= cnt; t += 8) {
            int sA = __shfl(sv, t + 0 + half);
            int sB = __shfl(sv, t + 2 + half);
            int sC = __shfl(sv, t + 4 + half);
            int sD = __shfl(sv, t + 6 + half);
            f16x4 hA = H4[(size_t)sA * 32 + fpos];
            f16x4 hB = H4[(size_t)sB * 32 + fpos];
            f16x4 hC = H4[(size_t)sC * 32 + fpos];
            f16x4 hD = H4[(size_t)sD * 32 + fpos];
#pragma unroll
            for (int q = 0; q < 4; ++q) {
                a0[q] += (float)hA[q];
                a1[q] += (float)hB[q];
                a2[q] += (float)hC[q];
                a3[q] += (float)hD[q];
            }
        }
        for (; t + 2 <= cnt; t += 2) {
            int sA = __shfl(sv, t + half);
            f16x4 hA = H4[(size_t)sA * 32 + fpos];
#pragma unroll
            for (int q = 0; q < 4; ++q) a0[q] += (float)hA[q];
        }
        if (t < cnt) {
            int sA = __shfl(sv, t);
            f16x4 hA = H4[(size_t)sA * 32 + fpos];
            if (half == 0) {
#pragma unroll
                for (int q = 0; q < 4; ++q) a0[q] += (float)hA[q];
            }
        }
        j += cnt;
    }
    float dv = dinv[wave];
    f32x4 a;
#pragma unroll
    for (int q = 0; q < 4; ++q) {
        float v = a0[q] + a1[q] + a2[q] + a3[q];
        v += __shfl_xor(v, 32);
        a[q] = v * dv;
    }
    if (half == 0)
        ((f32x4*)Hout)[(size_t)wave * 32 + fpos] = a;
}

// ---------- mean-pool split: G*8 partial-sum blocks, then tiny readout ----------
__global__ __launch_bounds__(256) void pool_partial(const float* __restrict__ H,
                                                    const int* __restrict__ gstart,
                                                    float* __restrict__ part) {
    int g = blockIdx.x >> 3, s = blockIdx.x & 7;
    int tid = threadIdx.x;
    int f = tid & 127, half = tid >> 7;
    int s0 = gstart[g], e0 = gstart[g + 1];
    int len = e0 - s0;
    int chunk = (len + 7) >> 3;
    int rs = s0 + s * chunk;
    int re = rs + chunk; if (re > e0) re = e0;
    float sum = 0.f;
    for (int n = rs + half; n < re; n += 2)
        sum += H[(size_t)n * C_HID + f];
    part[(size_t)blockIdx.x * 256 + tid] = sum;
}

__global__ __launch_bounds__(256) void pool_readout(const float* __restrict__ part, const int* __restrict__ gstart,
                                                    const float* __restrict__ B, void* __restrict__ out,
                                                    const int* __restrict__ flagp) {
    __shared__ float phi[2048];
    __shared__ float red[256];
    __shared__ float partl[8][32];
    const int is_f32 = *flagp;
    int g = blockIdx.x;
    int tid = threadIdx.x;
    float sum = 0.f;
#pragma unroll
    for (int s = 0; s < 8; ++s)
        sum += part[((size_t)g * 8 + s) * 256 + tid];
    red[tid] = sum;
    __syncthreads();
    if (tid < 128) {
        int s0 = gstart[g], e0 = gstart[g + 1];
        float cnt = fmaxf((float)(e0 - s0), 1.0f);
        float x = (red[tid] + red[tid + 128]) / cnt;
        float s1, c1;
        __sincosf(x, &s1, &c1);
        phi[tid * 16 + 0] = c1; phi[tid * 16 + 8] = s1;
        float ck = c1, sk = s1;
#pragma unroll
        for (int h = 1; h < 8; ++h) {
            float cn = ck * c1 - sk * s1;
            float sn = sk * c1 + ck * s1;
            phi[tid * 16 + h] = cn; phi[tid * 16 + 8 + h] = sn;
            ck = cn; sk = sn;
        }
    }
    __syncthreads();
    int o = tid & 31, p = tid >> 5;
    float acc = 0.f;
    for (int k = p * 256; k < p * 256 + 256; ++k)
        acc = fmaf(phi[k], B[k * C_LAT + o], acc);
    partl[p][o] = acc;
    __syncthreads();
    if (tid < 32) {
        float s = 0.f;
#pragma unroll
        for (int pp = 0; pp < 8; ++pp) s += partl[pp][tid];
        if (is_f32) ((float*)out)[g * C_LAT + tid] = s;
        else        ((bf16*)out)[g * C_LAT + tid] = __float2bfloat16(s);
    }
}

extern "C" void kernel_launch(void* const* d_in, const int* in_sizes, int n_in,
                              void* d_out, int out_size, void* d_ws, size_t ws_size,
                              hipStream_t stream) {
    const void* features = d_in[0];
    const int*  edge     = (const int*)d_in[1];
    const int*  batch    = (const int*)d_in[2];
    const void* W_embed  = d_in[3];
    const void* W_mp     = d_in[4];
    const void* W_read   = d_in[5];

    const int N = in_sizes[0] / C_IN;
    const int E = in_sizes[1] / 2;
    const int* row = edge;
    const int* col = edge + E;
    const int nScanBlocks = (N + 1023) / 1024;
    const bool packed_ok = (N <= 65536);

    char* ws = (char*)d_ws;
    auto alloc = [&](size_t bytes) { char* p = ws; ws += (bytes + 255) & ~(size_t)255; return p; };
    float* h_a    = (float*)alloc((size_t)N * C_HID * 4);
    f16*   h16    = (f16*)alloc((size_t)N * C_HID * 2);
    f16*   Bte    = (f16*)alloc((size_t)16 * 4 * 256 * 8 * 2);          // 256 KB
    f16*   Btmp   = (f16*)alloc((size_t)C_L * 32 * 4 * 256 * 8 * 2);    // 1.5 MB
    float* Brd    = (float*)alloc((size_t)2048 * C_LAT * 4);
    float* ppart  = (float*)alloc((size_t)C_G * 8 * 256 * 4);           // 512 KB
    int*   deg    = (int*)alloc((size_t)N * 4);
    float* dinv   = (float*)alloc((size_t)N * 4);
    int*   rowptr = (int*)alloc((size_t)(N + 1) * 4);
    int*   cursor = (int*)alloc((size_t)N * 4);
    unsigned short* srcs16 = (unsigned short*)alloc((size_t)(E + N) * 2);
    int*   srcs32 = (int*)alloc(packed_ok ? 256 : (size_t)(E + N) * 4);
    int*   bsum   = (int*)alloc((size_t)nScanBlocks * 4);
    int*   gstart = (int*)alloc((size_t)(C_G + 1) * 4);
    int*   dflag  = (int*)alloc(256);

    hipMemsetAsync(deg, 0, (size_t)N * 4, stream);
    hipMemsetAsync(cursor, 0, (size_t)N * 4, stream);

    detect_dtype<<<1, 256, 0, stream>>>((const unsigned short*)W_embed, dflag);

    repack_embed<<<(16 * 4 * 256 * 8 + 255) / 256, 256, 0, stream>>>(W_embed, Bte, dflag);
    repack_mp<<<(C_L * 32 * 4 * 256 * 8 + 255) / 256, 256, 0, stream>>>(W_mp, Btmp, dflag);
    repack_read<<<(2 * C_LAT * C_HID * C_H + 255) / 256, 256, 0, stream>>>(W_read, Brd, dflag);

    deg_count<<<(E + N + 255) / 256, 256, 0, stream>>>(col, deg, E, N);
    dinv_kernel<<<(N + 255) / 256, 256, 0, stream>>>(deg, dinv, N);
    graph_bounds<<<1, 128, 0, stream>>>(batch, gstart, N);
    scan1<<<nScanBlocks, 1024, 0, stream>>>(deg, rowptr, bsum, N);
    scan2<<<1, 64, 0, stream>>>(bsum, nScanBlocks);
    scan3<<<nScanBlocks, 1024, 0, stream>>>(rowptr, bsum, N);
    if (packed_ok) {
        const int nchunks = 256;
        csr_fill_part<<<nchunks * 8, 256, 0, stream>>>(row, col, rowptr, cursor, srcs16, E, N, nchunks);
    } else {
        csr_fill<<<(E + N + 255) / 256, 256, 0, stream>>>(row, col, rowptr, cursor, srcs32, E, N);
    }

    const int gemm_grid = (N + 63) / 64;
    kan_gemm_mfma<C_IN, false><<<gemm_grid, 256, 0, stream>>>(features, Bte, h_a, nullptr, nullptr, N, dflag);
    for (int l = 0; l < C_L; ++l) {
        kan_gemm_mfma<C_HID, true><<<gemm_grid, 256, 0, stream>>>(h_a, Btmp + (size_t)l * 32 * 4 * 256 * 8,
                                                                  nullptr, h16, dinv, N, nullptr);
        if (packed_ok)
            aggregate<unsigned short><<<((size_t)N * 64 + 255) / 256, 256, 0, stream>>>(h16, h_a, rowptr, srcs16, dinv, N);
        else
            aggregate<int><<<((size_t)N * 64 + 255) / 256, 256, 0, stream>>>(h16, h_a, rowptr, srcs32, dinv, N);
    }

    pool_partial<<<C_G * 8, 256, 0, stream>>>(h_a, gstart, ppart);
    pool_readout<<<C_G, 256, 0, stream>>>(ppart, gstart, Brd, d_out, dflag);
}